// Round 18
// baseline (188.022 us; speedup 1.0000x reference)
//
#include <hip/hip_runtime.h>
#include <hip/hip_bf16.h>

// CausalSelfAttention: x[4,2048,1024] -> qkv proj -> 16-head causal attn -> out proj
// Pipeline: cvt3 -> gemm_bt<QKV> (counted vmcnt, XOR swizzle, LDS-transposed
// V epilogue) -> attn (paired bands INTERLEAVED, KVBLK=128, defer-max,
// per-band P buffers, no explicit P-path waits) -> gemm_bt<OUT>

#define B_ 4
#define T_ 2048
#define C_ 1024
#define H_ 16
#define D_ 64
#define M_ (B_*T_)   // 8192 tokens

#define SCALE_LOG2 0.18033688f   // (1/sqrt(64)) * log2(e), folded into Q in GEMM

typedef __attribute__((ext_vector_type(8))) short short8;
typedef __attribute__((ext_vector_type(4))) float f32x4;
typedef __attribute__((ext_vector_type(16))) float f32x16;

static __device__ __forceinline__ ushort f2bf(float f) {
  __hip_bfloat16 b = __float2bfloat16(f);
  ushort u; __builtin_memcpy(&u, &b, 2); return u;
}

static __device__ __forceinline__ void ld16(const void* g, void* l) {
  __builtin_amdgcn_global_load_lds((const __attribute__((address_space(1))) void*)g,
                                   (__attribute__((address_space(3))) void*)l, 16, 0, 0);
}

static __device__ __forceinline__ f32x4 mfma16(short8 a, short8 b, f32x4 c) {
  return __builtin_amdgcn_mfma_f32_16x16x32_bf16(a, b, c, 0, 0, 0);
}
static __device__ __forceinline__ f32x16 mfma32(short8 a, short8 b, f32x16 c) {
  return __builtin_amdgcn_mfma_f32_32x32x16_bf16(a, b, c, 0, 0, 0);
}

static __device__ __forceinline__ float pair_max(float x) {
  return fmaxf(x, __shfl_xor(x, 32));
}
static __device__ __forceinline__ float pair_sum(float x) {
  return x + __shfl_xor(x, 32);
}

// ---------------- fp32 -> bf16 convert, all three tensors in one launch ----
__global__ void cvt3(const float* __restrict__ a, const float* __restrict__ b,
                     const float* __restrict__ c, ushort* __restrict__ oa,
                     ushort* __restrict__ ob, ushort* __restrict__ oc,
                     int na, int nb, int nc) {
  int tot = na + nb + nc;
  int i = blockIdx.x * blockDim.x + threadIdx.x;
  int st = gridDim.x * blockDim.x;
  for (; i < tot; i += st) {
    const float* s; ushort* d; int k = i;
    if (k < na)            { s = a; d = oa; }
    else if (k < na + nb)  { k -= na; s = b; d = ob; }
    else                   { k -= na + nb; s = c; d = oc; }
    float4 v = ((const float4*)s)[k];
    ushort4 o;
    o.x = f2bf(v.x); o.y = f2bf(v.y); o.z = f2bf(v.z); o.w = f2bf(v.w);
    ((ushort4*)d)[k] = o;
  }
}

// ---------------- C = A @ B^T + bias (both A,B K-major bf16) ----------------
// Counted-vmcnt dbuf pipeline + granule-XOR swizzle (0 conflicts). MODE 0:
// QKV -> q (pre-scaled exp2 domain), k, vt[B,H,D,T]; V-third blocks route the
// epilogue through an LDS transpose (stride-136) for coalesced-along-t stores.
// MODE 1: out projection -> fp32 d_out.
template<int MODE>
__global__ __launch_bounds__(256) void gemm_bt(
    const ushort* __restrict__ A, const ushort* __restrict__ Bm,
    const float* __restrict__ bias, int K,
    ushort* __restrict__ q, ushort* __restrict__ kk, ushort* __restrict__ vt,
    float* __restrict__ outF)
{
  __shared__ ushort SM[17408];
  const int tid = threadIdx.x;
  const int lane = tid & 63;
  const int w = tid >> 6;
  const int wr = w >> 1, wc = w & 1;
  const int l15 = lane & 15, lhi = lane >> 4;
  const long i0 = (long)blockIdx.y * 128;
  const long j0 = (long)blockIdx.x * 128;

  const int gsw = (lhi ^ ((l15 >> 1) & 3)) * 8;

  auto STAGE = [&](int buf, int k0) {
    int c = tid;
    int row = c >> 2, gs = (c & 3) ^ ((row >> 1) & 3);
    ld16((const char*)A  + ((i0 + row) * K + k0 + gs * 8) * 2, (char*)SM + buf*8192 + c*16);
    ld16((const char*)Bm + ((j0 + row) * K + k0 + gs * 8) * 2, (char*)SM + 16384 + buf*8192 + c*16);
    c = tid + 256;
    row = c >> 2; gs = (c & 3) ^ ((row >> 1) & 3);
    ld16((const char*)A  + ((i0 + row) * K + k0 + gs * 8) * 2, (char*)SM + buf*8192 + c*16);
    ld16((const char*)Bm + ((j0 + row) * K + k0 + gs * 8) * 2, (char*)SM + 16384 + buf*8192 + c*16);
  };

  f32x4 acc[4][4] = {};
  const int nsteps = K >> 5;

  STAGE(0, 0);
  STAGE(1, 32);
  int cur = 0;

  for (int t = 0; t < nsteps; t++) {
    if (t + 1 < nsteps) { asm volatile("s_waitcnt vmcnt(4)" ::: "memory"); }
    else                { asm volatile("s_waitcnt vmcnt(0)" ::: "memory"); }
    __builtin_amdgcn_s_barrier();
    __builtin_amdgcn_sched_barrier(0);

    short8 af[4], bf[4];
#pragma unroll
    for (int m = 0; m < 4; m++)
      af[m] = *(const short8*)&SM[cur*4096 + (wr*64 + m*16 + l15)*32 + gsw];
#pragma unroll
    for (int n = 0; n < 4; n++)
      bf[n] = *(const short8*)&SM[8192 + cur*4096 + (wc*64 + n*16 + l15)*32 + gsw];
    __builtin_amdgcn_s_setprio(1);
#pragma unroll
    for (int m = 0; m < 4; m++)
#pragma unroll
      for (int n = 0; n < 4; n++)
        acc[m][n] = mfma16(af[m], bf[n], acc[m][n]);
    __builtin_amdgcn_s_setprio(0);

    __builtin_amdgcn_s_barrier();
    __builtin_amdgcn_sched_barrier(0);
    if (t + 2 < nsteps) STAGE(cur, (t + 2) * 32);
    cur ^= 1;
  }

  if (MODE == 0 && j0 >= 2048) {
    // V block: LDS transpose epilogue (write [jl][tl] stride 136, read along t)
#pragma unroll
    for (int m = 0; m < 4; m++)
#pragma unroll
      for (int n = 0; n < 4; n++) {
        const int jl = wc*64 + n*16 + l15;
        const int tl = wr*64 + m*16 + lhi*4;
        const float bs = bias[j0 + jl];
        uint w0, w1;
        asm("v_cvt_pk_bf16_f32 %0, %1, %2" : "=v"(w0)
            : "v"(acc[m][n][0] + bs), "v"(acc[m][n][1] + bs));
        asm("v_cvt_pk_bf16_f32 %0, %1, %2" : "=v"(w1)
            : "v"(acc[m][n][2] + bs), "v"(acc[m][n][3] + bs));
        uint2 pr; pr.x = w0; pr.y = w1;
        *(uint2*)&SM[jl * 136 + tl] = pr;
      }
    __syncthreads();
    const int b = (int)(i0 >> 11);
    const int tb = (int)(i0 & 2047);
#pragma unroll
    for (int k2 = 0; k2 < 8; k2++) {
      const int chunk = k2 * 256 + tid;
      const int jl = chunk >> 4;
      const int t0 = (chunk & 15) * 8;
      uint4 pw = *(const uint4*)&SM[jl * 136 + t0];
      const int cc = (int)((j0 + jl) & 1023);
      const int h = cc >> 6, d = cc & 63;
      *(uint4*)&vt[((size_t)(b * H_ + h) * D_ + d) * T_ + tb + t0] = pw;
    }
  } else {
#pragma unroll
    for (int m = 0; m < 4; m++) {
#pragma unroll
      for (int n = 0; n < 4; n++) {
#pragma unroll
        for (int r = 0; r < 4; r++) {
          long i = i0 + wr*64 + m*16 + lhi*4 + r;
          int  j = (int)j0 + wc*64 + n*16 + l15;
          float v = acc[m][n][r] + bias[j];
          if (MODE == 0) {
            int b = (int)(i >> 11), t = (int)(i & 2047);
            int cc = j & 1023;
            int h = cc >> 6, d = cc & 63;
            long bh = (long)b * H_ + h;
            if (j < 1024)      q [(bh*T_ + t)*D_ + d] = f2bf(v * SCALE_LOG2);
            else               kk[(bh*T_ + t)*D_ + d] = f2bf(v);
          } else {
            outF[i * C_ + j] = v;
          }
        }
      }
    }
  }
}

// ------- causal flash attention, interleaved paired bands, KVBLK=128 -------
// 512 blocks x 256 threads (4 waves). head = bb&63 (8 heads/XCD), i = bb>>6,
// J = i<4 ? i : 11-i (co-resident bb, bb+256 sum to constant work). Wave w:
// band a rows [128J+32w,+31], band b rows mirror. K[128][64] + Vt[64][128]
// double-buffered (counted vmcnt(8), XOR granule swizzle). Per 32-kv chunk:
// BOTH bands' QK MFMAs issue together; both softmax chains (defer-max,
// lane-partial l) run as independent register streams (ILP); P goes through
// per-band wave-private LDS buffers with NO explicit waits (same-wave DS is
// in-order; compiler guards the read->MFMA dep). LDS exactly 80KB -> 2/CU.
#define PSTR 16   // u32 per q-row

// softmax compute phase: mask, defer-max, exp2, lane-partial sum, pack -> W[8]
static __device__ __forceinline__ void sm_compute(
    f32x16& sc, float& m, float& lp, f32x16 (&o)[2],
    int q0, int kvbase, int l31, int hi, uint (&W)[8])
{
  float sv[16];
  const bool needmask = (kvbase + 31 > q0);
#pragma unroll
  for (int r = 0; r < 16; r++) {
    float xv = sc[r];
    if (needmask) {
      int kv = kvbase + (r & 3) + 8 * (r >> 2) + 4 * hi;
      if (kv > q0 + l31) xv = -1e30f;
    }
    sv[r] = xv;
  }
  float a0 = fmaxf(fmaxf(sv[0], sv[1]), sv[2]);
  float a1 = fmaxf(fmaxf(sv[3], sv[4]), sv[5]);
  float a2 = fmaxf(fmaxf(sv[6], sv[7]), sv[8]);
  float a3 = fmaxf(fmaxf(sv[9], sv[10]), sv[11]);
  float a4 = fmaxf(fmaxf(sv[12], sv[13]), sv[14]);
  float pmax = fmaxf(fmaxf(fmaxf(a0, a1), a2), fmaxf(fmaxf(a3, a4), sv[15]));
  if (__any(pmax > m + 8.0f)) {
    float rowm = pair_max(pmax);
    float nm = fmaxf(m, rowm);
    float alpha = __builtin_amdgcn_exp2f(m - nm);
    m = nm;
    lp *= alpha;
#pragma unroll
    for (int dt = 0; dt < 2; dt++)
#pragma unroll
      for (int r = 0; r < 16; r++) o[dt][r] *= alpha;
  }
  float s = 0.f;
#pragma unroll
  for (int r = 0; r < 16; r++) {
    float p = __builtin_amdgcn_exp2f(sv[r] - m);
    sv[r] = p;
    s += p;
  }
  lp += s;
#pragma unroll
  for (int r = 0; r < 8; r++)
    asm("v_cvt_pk_bf16_f32 %0, %1, %2" : "=v"(W[r]) : "v"(sv[2*r]), "v"(sv[2*r+1]));
}

__global__ __launch_bounds__(256, 2) void attn_k(
    const ushort* __restrict__ Q, const ushort* __restrict__ K,
    const ushort* __restrict__ V, ushort* __restrict__ AO)
{
  __shared__ ushort Kt[2][128*64];
  __shared__ ushort Vt[2][64*128];
  __shared__ uint P2[8][32 * PSTR];    // per-band wave-private buffers
  const int tid = threadIdx.x;
  const int lane = tid & 63;
  const int w = tid >> 6;              // 0..3
  const int l31 = lane & 31, hi = lane >> 5;
  const int bb = blockIdx.x;
  const int head = bb & 63;            // bb%8 = head%8 -> same-head same XCD
  const int i = bb >> 6;               // 0..7
  const int J = (i < 4) ? i : 11 - i;  // complementary pairing bb, bb+256
  const int nst = 16 - J;              // 128-kv tiles (>= 9)
  const int q0a = 128 * J + 32 * w;            // low band
  const int q0b = 2016 - 128 * J - 32 * w;     // high (mirror) band

  const ushort* Qb = Q + (size_t)head * T_ * D_;
  const ushort* Kb = K + (size_t)head * T_ * D_;
  const ushort* Vb = V + (size_t)head * D_ * T_;   // [d][t]

  auto STAGE = [&](int buf, int kv0s) {
#pragma unroll
    for (int hb = 0; hb < 4; hb++) {
      int slot = tid + hb * 256;            // 0..1023
      int krow = slot >> 3, kg = slot & 7, kgs = kg ^ (krow & 7);
      ld16((const char*)Kb + ((size_t)(kv0s + krow) * D_ + kgs * 8) * 2,
           (char*)&Kt[buf][0] + slot * 16);
      int vrow = slot >> 4, vg = slot & 15, vgs = vg ^ (vrow & 15);
      ld16((const char*)Vb + ((size_t)vrow * T_ + kv0s + vgs * 8) * 2,
           (char*)&Vt[buf][0] + slot * 16);
    }
  };

  // Q as B-fragment: lane holds Q[q0+l31][d = s*16 + hi*8 + e] per slice s.
  short8 qfa[4], qfb[4];
#pragma unroll
  for (int s = 0; s < 4; s++) {
    qfa[s] = *(const short8*)&Qb[(q0a + l31) * D_ + s*16 + hi*8];
    qfb[s] = *(const short8*)&Qb[(q0b + l31) * D_ + s*16 + hi*8];
  }

  f32x16 oa[2] = {}, ob[2] = {};       // O'[d][q]: d = dt*32 + (r&3)+8(r>>2)+4hi
  float ma = -1e30f, la = 0.f, mb = -1e30f, lb = 0.f;

  STAGE(0, 0);
  STAGE(1, 128);
  int cur = 0;
  uint* Pb = &P2[w*2][0];
  uint* Pa = &P2[w*2+1][0];

  for (int t = 0; t < nst; t++) {
    const int kv0 = t * 128;
    if (t + 1 < nst) { asm volatile("s_waitcnt vmcnt(8)" ::: "memory"); }
    else             { asm volatile("s_waitcnt vmcnt(0)" ::: "memory"); }
    __builtin_amdgcn_s_barrier();
    __builtin_amdgcn_sched_barrier(0);

#pragma unroll
    for (int c = 0; c < 4; c++) {
      const int kvc = kv0 + 32 * c;
      const bool act_b = (kvc <= q0b + 31);
      const bool act_a = (kvc <= q0a + 31);   // act_a implies act_b
      if (act_b) {
        // K A-fragment: lane holds K[c*32+l31][d = s*16 + hi*8 + e]
        short8 kf[4];
#pragma unroll
        for (int s = 0; s < 4; s++) {
          const int row = c*32 + l31;
          kf[s] = *(const short8*)&Kt[cur][row*64 + (((2*s + hi) ^ (row & 7)) << 3)];
        }
        // Vt A-fragment: Vt[dt*32+l31][kv = c*32 + sl*16 + hi*8 + e] (early issue)
        short8 vf[2][2];
#pragma unroll
        for (int sl = 0; sl < 2; sl++)
#pragma unroll
          for (int dt = 0; dt < 2; dt++) {
            const int row = dt*32 + l31;
            const int u = c*4 + sl*2 + hi;
            vf[sl][dt] = *(const short8*)
                &Vt[cur][row*128 + ((u ^ (row & 15)) << 3)];
          }

        // QK for BOTH bands (8 independent MFMAs)
        f32x16 scb = {}, sca = {};
        __builtin_amdgcn_s_setprio(1);
#pragma unroll
        for (int s = 0; s < 4; s++) scb = mfma32(kf[s], qfb[s], scb);
        if (act_a) {
#pragma unroll
          for (int s = 0; s < 4; s++) sca = mfma32(kf[s], qfa[s], sca);
        }
        __builtin_amdgcn_s_setprio(0);

        // Softmax for both bands: independent register streams (ILP)
        uint Wb[8], Wa[8];
        sm_compute(scb, mb, lb, ob, q0b, kvc, l31, hi, Wb);
        if (act_a) sm_compute(sca, ma, la, oa, q0a, kvc, l31, hi, Wa);

        // P store + read, per-band buffers; same-wave DS in-order, no waits.
#pragma unroll
        for (int r2 = 0; r2 < 4; r2++) {
          uint2 pr; pr.x = Wb[2*r2]; pr.y = Wb[2*r2 + 1];
          *(uint2*)&Pb[l31 * PSTR + r2*4 + 2*hi] = pr;
        }
        if (act_a) {
#pragma unroll
          for (int r2 = 0; r2 < 4; r2++) {
            uint2 pr; pr.x = Wa[2*r2]; pr.y = Wa[2*r2 + 1];
            *(uint2*)&Pa[l31 * PSTR + r2*4 + 2*hi] = pr;
          }
        }
        short8 pfb[2], pfa[2];
#pragma unroll
        for (int sl = 0; sl < 2; sl++) {
          uint4 pw = *(const uint4*)&Pb[l31 * PSTR + sl*8 + hi*4];
          __builtin_memcpy(&pfb[sl], &pw, 16);
        }
        if (act_a) {
#pragma unroll
          for (int sl = 0; sl < 2; sl++) {
            uint4 pw = *(const uint4*)&Pa[l31 * PSTR + sl*8 + hi*4];
            __builtin_memcpy(&pfa[sl], &pw, 16);
          }
        }

        // PV for both bands
        __builtin_amdgcn_s_setprio(1);
#pragma unroll
        for (int sl = 0; sl < 2; sl++)
#pragma unroll
          for (int dt = 0; dt < 2; dt++)
            ob[dt] = mfma32(vf[sl][dt], pfb[sl], ob[dt]);
        if (act_a) {
#pragma unroll
          for (int sl = 0; sl < 2; sl++)
#pragma unroll
            for (int dt = 0; dt < 2; dt++)
              oa[dt] = mfma32(vf[sl][dt], pfa[sl], oa[dt]);
        }
        __builtin_amdgcn_s_setprio(0);
      }
    }

    __builtin_amdgcn_s_barrier();
    __builtin_amdgcn_sched_barrier(0);
    if (t + 2 < nst) STAGE(cur, kv0 + 256);   // overwrite freed buffer
    cur ^= 1;
  }

  const int b = head >> 4, h = head & 15;
  {
    const float invl = 1.0f / pair_sum(lb);
    const size_t rowb = (size_t)(b * T_ + q0b + l31) * C_ + h * 64;
#pragma unroll
    for (int dt = 0; dt < 2; dt++)
#pragma unroll
      for (int rg = 0; rg < 4; rg++) {
        const int d0 = dt*32 + 8*rg + 4*hi;
        ushort4 ov;
        ov.x = f2bf(ob[dt][rg*4+0] * invl);
        ov.y = f2bf(ob[dt][rg*4+1] * invl);
        ov.z = f2bf(ob[dt][rg*4+2] * invl);
        ov.w = f2bf(ob[dt][rg*4+3] * invl);
        *(ushort4*)&AO[rowb + d0] = ov;
      }
  }
  {
    const float invl = 1.0f / pair_sum(la);
    const size_t rowb = (size_t)(b * T_ + q0a + l31) * C_ + h * 64;
#pragma unroll
    for (int dt = 0; dt < 2; dt++)
#pragma unroll
      for (int rg = 0; rg < 4; rg++) {
        const int d0 = dt*32 + 8*rg + 4*hi;
        ushort4 ov;
        ov.x = f2bf(oa[dt][rg*4+0] * invl);
        ov.y = f2bf(oa[dt][rg*4+1] * invl);
        ov.z = f2bf(oa[dt][rg*4+2] * invl);
        ov.w = f2bf(oa[dt][rg*4+3] * invl);
        *(ushort4*)&AO[rowb + d0] = ov;
      }
  }
}

extern "C" void kernel_launch(void* const* d_in, const int* in_sizes, int n_in,
                              void* d_out, int out_size, void* d_ws, size_t ws_size,
                              hipStream_t stream) {
  const float* x     = (const float*)d_in[0];
  const float* w_qkv = (const float*)d_in[1];
  const float* b_qkv = (const float*)d_in[2];
  const float* w_out = (const float*)d_in[3];
  const float* b_out = (const float*)d_in[4];
  float* out = (float*)d_out;

  ushort* xb    = (ushort*)d_ws;                    // 8192*1024
  ushort* wqkvb = xb    + (size_t)M_ * C_;          // 3072*1024
  ushort* woutb = wqkvb + (size_t)3 * C_ * C_;      // 1024*1024
  ushort* q     = woutb + (size_t)C_ * C_;          // [B,H,T,D] (exp2-domain scaled)
  ushort* kk    = q     + (size_t)M_ * C_;          // [B,H,T,D]
  ushort* vt    = kk    + (size_t)M_ * C_;          // [B,H,D,T]
  ushort* ao    = xb;                               // reuse xb (free after QKV GEMM)

  cvt3<<<2048, 256, 0, stream>>>(x, w_qkv, w_out, xb, wqkvb, woutb,
                                 (M_ * C_) / 4, (3 * C_ * C_) / 4, (C_ * C_) / 4);

  gemm_bt<0><<<dim3(3 * C_ / 128, M_ / 128), 256, 0, stream>>>(
      xb, wqkvb, b_qkv, C_, q, kk, vt, nullptr);

  // 4 waves x (32 low + 32 high) rows = 256 rows per block -> 512 blocks.
  attn_k<<<B_ * H_ * T_ / 256, 256, 0, stream>>>(q, kk, vt, ao);

  gemm_bt<1><<<dim3(C_ / 128, M_ / 128), 256, 0, stream>>>(
      ao, woutb, b_out, C_, nullptr, nullptr, nullptr, out);
}

// Round 19
// 171.618 us; speedup vs baseline: 1.0956x; 1.0956x over previous
//
#include <hip/hip_runtime.h>
#include <hip/hip_bf16.h>

// CausalSelfAttention: x[4,2048,1024] -> qkv proj -> 16-head causal attn -> out proj
// Pipeline: cvt3 -> gemm_bt<QKV> (counted vmcnt, XOR swizzle, LDS-transposed
// V epilogue) -> attn (paired bands, KVBLK=128, defer-max, rotated P slots)
// -> gemm_bt<OUT>

#define B_ 4
#define T_ 2048
#define C_ 1024
#define H_ 16
#define D_ 64
#define M_ (B_*T_)   // 8192 tokens

#define SCALE_LOG2 0.18033688f   // (1/sqrt(64)) * log2(e), folded into Q in GEMM

typedef __attribute__((ext_vector_type(8))) short short8;
typedef __attribute__((ext_vector_type(4))) float f32x4;
typedef __attribute__((ext_vector_type(16))) float f32x16;

static __device__ __forceinline__ ushort f2bf(float f) {
  __hip_bfloat16 b = __float2bfloat16(f);
  ushort u; __builtin_memcpy(&u, &b, 2); return u;
}

static __device__ __forceinline__ void ld16(const void* g, void* l) {
  __builtin_amdgcn_global_load_lds((const __attribute__((address_space(1))) void*)g,
                                   (__attribute__((address_space(3))) void*)l, 16, 0, 0);
}

static __device__ __forceinline__ f32x4 mfma16(short8 a, short8 b, f32x4 c) {
  return __builtin_amdgcn_mfma_f32_16x16x32_bf16(a, b, c, 0, 0, 0);
}
static __device__ __forceinline__ f32x16 mfma32(short8 a, short8 b, f32x16 c) {
  return __builtin_amdgcn_mfma_f32_32x32x16_bf16(a, b, c, 0, 0, 0);
}

static __device__ __forceinline__ float pair_max(float x) {
  return fmaxf(x, __shfl_xor(x, 32));
}
static __device__ __forceinline__ float pair_sum(float x) {
  return x + __shfl_xor(x, 32);
}

// ---------------- fp32 -> bf16 convert, all three tensors in one launch ----
__global__ void cvt3(const float* __restrict__ a, const float* __restrict__ b,
                     const float* __restrict__ c, ushort* __restrict__ oa,
                     ushort* __restrict__ ob, ushort* __restrict__ oc,
                     int na, int nb, int nc) {
  int tot = na + nb + nc;
  int i = blockIdx.x * blockDim.x + threadIdx.x;
  int st = gridDim.x * blockDim.x;
  for (; i < tot; i += st) {
    const float* s; ushort* d; int k = i;
    if (k < na)            { s = a; d = oa; }
    else if (k < na + nb)  { k -= na; s = b; d = ob; }
    else                   { k -= na + nb; s = c; d = oc; }
    float4 v = ((const float4*)s)[k];
    ushort4 o;
    o.x = f2bf(v.x); o.y = f2bf(v.y); o.z = f2bf(v.z); o.w = f2bf(v.w);
    ((ushort4*)d)[k] = o;
  }
}

// ---------------- C = A @ B^T + bias (both A,B K-major bf16) ----------------
// Counted-vmcnt dbuf pipeline + granule-XOR swizzle (0 conflicts). MODE 0:
// QKV -> q (pre-scaled exp2 domain), k, vt[B,H,D,T]; V-third blocks route the
// epilogue through an LDS transpose (stride-136) for coalesced-along-t stores.
// MODE 1: out projection -> fp32 d_out.
template<int MODE>
__global__ __launch_bounds__(256) void gemm_bt(
    const ushort* __restrict__ A, const ushort* __restrict__ Bm,
    const float* __restrict__ bias, int K,
    ushort* __restrict__ q, ushort* __restrict__ kk, ushort* __restrict__ vt,
    float* __restrict__ outF)
{
  __shared__ ushort SM[17408];
  const int tid = threadIdx.x;
  const int lane = tid & 63;
  const int w = tid >> 6;
  const int wr = w >> 1, wc = w & 1;
  const int l15 = lane & 15, lhi = lane >> 4;
  const long i0 = (long)blockIdx.y * 128;
  const long j0 = (long)blockIdx.x * 128;

  const int gsw = (lhi ^ ((l15 >> 1) & 3)) * 8;

  auto STAGE = [&](int buf, int k0) {
    int c = tid;
    int row = c >> 2, gs = (c & 3) ^ ((row >> 1) & 3);
    ld16((const char*)A  + ((i0 + row) * K + k0 + gs * 8) * 2, (char*)SM + buf*8192 + c*16);
    ld16((const char*)Bm + ((j0 + row) * K + k0 + gs * 8) * 2, (char*)SM + 16384 + buf*8192 + c*16);
    c = tid + 256;
    row = c >> 2; gs = (c & 3) ^ ((row >> 1) & 3);
    ld16((const char*)A  + ((i0 + row) * K + k0 + gs * 8) * 2, (char*)SM + buf*8192 + c*16);
    ld16((const char*)Bm + ((j0 + row) * K + k0 + gs * 8) * 2, (char*)SM + 16384 + buf*8192 + c*16);
  };

  f32x4 acc[4][4] = {};
  const int nsteps = K >> 5;

  STAGE(0, 0);
  STAGE(1, 32);
  int cur = 0;

  for (int t = 0; t < nsteps; t++) {
    if (t + 1 < nsteps) { asm volatile("s_waitcnt vmcnt(4)" ::: "memory"); }
    else                { asm volatile("s_waitcnt vmcnt(0)" ::: "memory"); }
    __builtin_amdgcn_s_barrier();
    __builtin_amdgcn_sched_barrier(0);

    short8 af[4], bf[4];
#pragma unroll
    for (int m = 0; m < 4; m++)
      af[m] = *(const short8*)&SM[cur*4096 + (wr*64 + m*16 + l15)*32 + gsw];
#pragma unroll
    for (int n = 0; n < 4; n++)
      bf[n] = *(const short8*)&SM[8192 + cur*4096 + (wc*64 + n*16 + l15)*32 + gsw];
    __builtin_amdgcn_s_setprio(1);
#pragma unroll
    for (int m = 0; m < 4; m++)
#pragma unroll
      for (int n = 0; n < 4; n++)
        acc[m][n] = mfma16(af[m], bf[n], acc[m][n]);
    __builtin_amdgcn_s_setprio(0);

    __builtin_amdgcn_s_barrier();
    __builtin_amdgcn_sched_barrier(0);
    if (t + 2 < nsteps) STAGE(cur, (t + 2) * 32);
    cur ^= 1;
  }

  if (MODE == 0 && j0 >= 2048) {
    // V block: LDS transpose epilogue (write [jl][tl] stride 136, read along t)
#pragma unroll
    for (int m = 0; m < 4; m++)
#pragma unroll
      for (int n = 0; n < 4; n++) {
        const int jl = wc*64 + n*16 + l15;
        const int tl = wr*64 + m*16 + lhi*4;
        const float bs = bias[j0 + jl];
        uint w0, w1;
        asm("v_cvt_pk_bf16_f32 %0, %1, %2" : "=v"(w0)
            : "v"(acc[m][n][0] + bs), "v"(acc[m][n][1] + bs));
        asm("v_cvt_pk_bf16_f32 %0, %1, %2" : "=v"(w1)
            : "v"(acc[m][n][2] + bs), "v"(acc[m][n][3] + bs));
        uint2 pr; pr.x = w0; pr.y = w1;
        *(uint2*)&SM[jl * 136 + tl] = pr;
      }
    __syncthreads();
    const int b = (int)(i0 >> 11);
    const int tb = (int)(i0 & 2047);
#pragma unroll
    for (int k2 = 0; k2 < 8; k2++) {
      const int chunk = k2 * 256 + tid;
      const int jl = chunk >> 4;
      const int t0 = (chunk & 15) * 8;
      uint4 pw = *(const uint4*)&SM[jl * 136 + t0];
      const int cc = (int)((j0 + jl) & 1023);
      const int h = cc >> 6, d = cc & 63;
      *(uint4*)&vt[((size_t)(b * H_ + h) * D_ + d) * T_ + tb + t0] = pw;
    }
  } else {
#pragma unroll
    for (int m = 0; m < 4; m++) {
#pragma unroll
      for (int n = 0; n < 4; n++) {
#pragma unroll
        for (int r = 0; r < 4; r++) {
          long i = i0 + wr*64 + m*16 + lhi*4 + r;
          int  j = (int)j0 + wc*64 + n*16 + l15;
          float v = acc[m][n][r] + bias[j];
          if (MODE == 0) {
            int b = (int)(i >> 11), t = (int)(i & 2047);
            int cc = j & 1023;
            int h = cc >> 6, d = cc & 63;
            long bh = (long)b * H_ + h;
            if (j < 1024)      q [(bh*T_ + t)*D_ + d] = f2bf(v * SCALE_LOG2);
            else               kk[(bh*T_ + t)*D_ + d] = f2bf(v);
          } else {
            outF[i * C_ + j] = v;
          }
        }
      }
    }
  }
}

// ------- causal flash attention, paired bands, KVBLK=128, defer-max -------
// r17 structure; P2 slot index ROTATED per row: phys = (logical +
// ((l31>>3)<<2)) & 15 on both write and read. Colliding lanes {l31, l31+8,
// +16, +24} (row stride 20 u32 -> same bank base) now map to bank-quads
// offset 0/4/8/12 -> conflict-free. Rotation is row-constant, 4-aligned,
// groups stay contiguous (no 16-wrap).
#define PSTR 20   // u32 per q-row: 16 pairs + 4 pad

static __device__ __forceinline__ void softmax_pack32(
    f32x16& sc, float& m, float& lp, f32x16 (&o)[2],
    int q0, int kvbase, int l31, int hi, int rot, uint* __restrict__ P)
{
  float sv[16];
  const bool needmask = (kvbase + 31 > q0);
#pragma unroll
  for (int r = 0; r < 16; r++) {
    float xv = sc[r];
    if (needmask) {
      int kv = kvbase + (r & 3) + 8 * (r >> 2) + 4 * hi;
      if (kv > q0 + l31) xv = -1e30f;
    }
    sv[r] = xv;
  }
  // lane max via max3-friendly triples
  float a0 = fmaxf(fmaxf(sv[0], sv[1]), sv[2]);
  float a1 = fmaxf(fmaxf(sv[3], sv[4]), sv[5]);
  float a2 = fmaxf(fmaxf(sv[6], sv[7]), sv[8]);
  float a3 = fmaxf(fmaxf(sv[9], sv[10]), sv[11]);
  float a4 = fmaxf(fmaxf(sv[12], sv[13]), sv[14]);
  float pmax = fmaxf(fmaxf(fmaxf(a0, a1), a2), fmaxf(fmaxf(a3, a4), sv[15]));
  // defer-max: rare rescale only on significant growth
  if (__any(pmax > m + 8.0f)) {
    float rowm = pair_max(pmax);
    float nm = fmaxf(m, rowm);
    float alpha = __builtin_amdgcn_exp2f(m - nm);
    m = nm;
    lp *= alpha;
#pragma unroll
    for (int dt = 0; dt < 2; dt++)
#pragma unroll
      for (int r = 0; r < 16; r++) o[dt][r] *= alpha;
  }
  float s = 0.f;
#pragma unroll
  for (int r = 0; r < 16; r++) {
    float p = __builtin_amdgcn_exp2f(sv[r] - m);
    sv[r] = p;
    s += p;
  }
  lp += s;
  uint W[8];
#pragma unroll
  for (int r = 0; r < 8; r++)
    asm("v_cvt_pk_bf16_f32 %0, %1, %2" : "=v"(W[r]) : "v"(sv[2*r]), "v"(sv[2*r+1]));
#pragma unroll
  for (int r2 = 0; r2 < 4; r2++) {
    uint2 pr; pr.x = W[2*r2]; pr.y = W[2*r2 + 1];
    *(uint2*)&P[l31 * PSTR + ((r2*4 + 2*hi + rot) & 15)] = pr;
  }
}

__global__ __launch_bounds__(256, 2) void attn_k(
    const ushort* __restrict__ Q, const ushort* __restrict__ K,
    const ushort* __restrict__ V, ushort* __restrict__ AO)
{
  __shared__ ushort Kt[2][128*64];
  __shared__ ushort Vt[2][64*128];
  __shared__ uint P2[4][32 * PSTR];
  const int tid = threadIdx.x;
  const int lane = tid & 63;
  const int w = tid >> 6;              // 0..3
  const int l31 = lane & 31, hi = lane >> 5;
  const int rot = ((l31 >> 3) & 3) << 2;   // row-constant slot rotation
  const int bb = blockIdx.x;
  const int head = bb & 63;            // bb%8 = head%8 -> same-head same XCD
  const int i = bb >> 6;               // 0..7
  const int J = (i < 4) ? i : 11 - i;  // complementary pairing bb, bb+256
  const int nst = 16 - J;              // 128-kv tiles (>= 9)
  const int q0a = 128 * J + 32 * w;            // low band
  const int q0b = 2016 - 128 * J - 32 * w;     // high (mirror) band

  const ushort* Qb = Q + (size_t)head * T_ * D_;
  const ushort* Kb = K + (size_t)head * T_ * D_;
  const ushort* Vb = V + (size_t)head * D_ * T_;   // [d][t]

  auto STAGE = [&](int buf, int kv0s) {
#pragma unroll
    for (int hb = 0; hb < 4; hb++) {
      int slot = tid + hb * 256;            // 0..1023
      int krow = slot >> 3, kg = slot & 7, kgs = kg ^ (krow & 7);
      ld16((const char*)Kb + ((size_t)(kv0s + krow) * D_ + kgs * 8) * 2,
           (char*)&Kt[buf][0] + slot * 16);
      int vrow = slot >> 4, vg = slot & 15, vgs = vg ^ (vrow & 15);
      ld16((const char*)Vb + ((size_t)vrow * T_ + kv0s + vgs * 8) * 2,
           (char*)&Vt[buf][0] + slot * 16);
    }
  };

  // Q as B-fragment: lane holds Q[q0+l31][d = s*16 + hi*8 + e] per slice s.
  short8 qfa[4], qfb[4];
#pragma unroll
  for (int s = 0; s < 4; s++) {
    qfa[s] = *(const short8*)&Qb[(q0a + l31) * D_ + s*16 + hi*8];
    qfb[s] = *(const short8*)&Qb[(q0b + l31) * D_ + s*16 + hi*8];
  }

  f32x16 oa[2] = {}, ob[2] = {};       // O'[d][q]: d = dt*32 + (r&3)+8(r>>2)+4hi
  float ma = -1e30f, la = 0.f, mb = -1e30f, lb = 0.f;

  STAGE(0, 0);
  STAGE(1, 128);
  int cur = 0;
  uint* P = &P2[w][0];

  for (int t = 0; t < nst; t++) {
    const int kv0 = t * 128;
    if (t + 1 < nst) { asm volatile("s_waitcnt vmcnt(8)" ::: "memory"); }
    else             { asm volatile("s_waitcnt vmcnt(0)" ::: "memory"); }
    __builtin_amdgcn_s_barrier();
    __builtin_amdgcn_sched_barrier(0);

#pragma unroll
    for (int c = 0; c < 4; c++) {
      const int kvc = kv0 + 32 * c;
      const bool act_b = (kvc <= q0b + 31);
      const bool act_a = (kvc <= q0a + 31);   // act_a implies act_b
      if (act_b) {
        // K A-fragment: lane holds K[c*32+l31][d = s*16 + hi*8 + e]
        short8 kf[4];
#pragma unroll
        for (int s = 0; s < 4; s++) {
          const int row = c*32 + l31;
          kf[s] = *(const short8*)&Kt[cur][row*64 + (((2*s + hi) ^ (row & 7)) << 3)];
        }
        // Vt A-fragment: Vt[dt*32+l31][kv = c*32 + sl*16 + hi*8 + e]
        short8 vf[2][2];
#pragma unroll
        for (int sl = 0; sl < 2; sl++)
#pragma unroll
          for (int dt = 0; dt < 2; dt++) {
            const int row = dt*32 + l31;
            const int u = c*4 + sl*2 + hi;
            vf[sl][dt] = *(const short8*)
                &Vt[cur][row*128 + ((u ^ (row & 15)) << 3)];
          }

        // ---- band b ----
        {
          f32x16 scb = {};
          __builtin_amdgcn_s_setprio(1);
#pragma unroll
          for (int s = 0; s < 4; s++) scb = mfma32(kf[s], qfb[s], scb);
          __builtin_amdgcn_s_setprio(0);
          softmax_pack32(scb, mb, lb, ob, q0b, kvc, l31, hi, rot, P);
          asm volatile("s_waitcnt lgkmcnt(0)" ::: "memory");
          __builtin_amdgcn_sched_barrier(0);
          short8 pf[2];
#pragma unroll
          for (int sl = 0; sl < 2; sl++) {
            uint4 pw = *(const uint4*)&P[l31 * PSTR + ((sl*8 + hi*4 + rot) & 15)];
            __builtin_memcpy(&pf[sl], &pw, 16);
          }
          __builtin_amdgcn_s_setprio(1);
#pragma unroll
          for (int sl = 0; sl < 2; sl++)
#pragma unroll
            for (int dt = 0; dt < 2; dt++)
              ob[dt] = mfma32(vf[sl][dt], pf[sl], ob[dt]);
          __builtin_amdgcn_s_setprio(0);
          __builtin_amdgcn_sched_barrier(0);
        }
        // ---- band a (reuses kf, vf, P buffer) ----
        if (act_a) {
          f32x16 sca = {};
          __builtin_amdgcn_s_setprio(1);
#pragma unroll
          for (int s = 0; s < 4; s++) sca = mfma32(kf[s], qfa[s], sca);
          __builtin_amdgcn_s_setprio(0);
          softmax_pack32(sca, ma, la, oa, q0a, kvc, l31, hi, rot, P);
          asm volatile("s_waitcnt lgkmcnt(0)" ::: "memory");
          __builtin_amdgcn_sched_barrier(0);
          short8 pf[2];
#pragma unroll
          for (int sl = 0; sl < 2; sl++) {
            uint4 pw = *(const uint4*)&P[l31 * PSTR + ((sl*8 + hi*4 + rot) & 15)];
            __builtin_memcpy(&pf[sl], &pw, 16);
          }
          __builtin_amdgcn_s_setprio(1);
#pragma unroll
          for (int sl = 0; sl < 2; sl++)
#pragma unroll
            for (int dt = 0; dt < 2; dt++)
              oa[dt] = mfma32(vf[sl][dt], pf[sl], oa[dt]);
          __builtin_amdgcn_s_setprio(0);
          __builtin_amdgcn_sched_barrier(0);
        }
      }
    }

    __builtin_amdgcn_s_barrier();
    __builtin_amdgcn_sched_barrier(0);
    if (t + 2 < nst) STAGE(cur, kv0 + 256);   // overwrite freed buffer
    cur ^= 1;
  }

  const int b = head >> 4, h = head & 15;
  {
    const float invl = 1.0f / pair_sum(lb);
    const size_t rowb = (size_t)(b * T_ + q0b + l31) * C_ + h * 64;
#pragma unroll
    for (int dt = 0; dt < 2; dt++)
#pragma unroll
      for (int rg = 0; rg < 4; rg++) {
        const int d0 = dt*32 + 8*rg + 4*hi;
        ushort4 ov;
        ov.x = f2bf(ob[dt][rg*4+0] * invl);
        ov.y = f2bf(ob[dt][rg*4+1] * invl);
        ov.z = f2bf(ob[dt][rg*4+2] * invl);
        ov.w = f2bf(ob[dt][rg*4+3] * invl);
        *(ushort4*)&AO[rowb + d0] = ov;
      }
  }
  {
    const float invl = 1.0f / pair_sum(la);
    const size_t rowb = (size_t)(b * T_ + q0a + l31) * C_ + h * 64;
#pragma unroll
    for (int dt = 0; dt < 2; dt++)
#pragma unroll
      for (int rg = 0; rg < 4; rg++) {
        const int d0 = dt*32 + 8*rg + 4*hi;
        ushort4 ov;
        ov.x = f2bf(oa[dt][rg*4+0] * invl);
        ov.y = f2bf(oa[dt][rg*4+1] * invl);
        ov.z = f2bf(oa[dt][rg*4+2] * invl);
        ov.w = f2bf(oa[dt][rg*4+3] * invl);
        *(ushort4*)&AO[rowb + d0] = ov;
      }
  }
}

extern "C" void kernel_launch(void* const* d_in, const int* in_sizes, int n_in,
                              void* d_out, int out_size, void* d_ws, size_t ws_size,
                              hipStream_t stream) {
  const float* x     = (const float*)d_in[0];
  const float* w_qkv = (const float*)d_in[1];
  const float* b_qkv = (const float*)d_in[2];
  const float* w_out = (const float*)d_in[3];
  const float* b_out = (const float*)d_in[4];
  float* out = (float*)d_out;

  ushort* xb    = (ushort*)d_ws;                    // 8192*1024
  ushort* wqkvb = xb    + (size_t)M_ * C_;          // 3072*1024
  ushort* woutb = wqkvb + (size_t)3 * C_ * C_;      // 1024*1024
  ushort* q     = woutb + (size_t)C_ * C_;          // [B,H,T,D] (exp2-domain scaled)
  ushort* kk    = q     + (size_t)M_ * C_;          // [B,H,T,D]
  ushort* vt    = kk    + (size_t)M_ * C_;          // [B,H,D,T]
  ushort* ao    = xb;                               // reuse xb (free after QKV GEMM)

  cvt3<<<2048, 256, 0, stream>>>(x, w_qkv, w_out, xb, wqkvb, woutb,
                                 (M_ * C_) / 4, (3 * C_ * C_) / 4, (C_ * C_) / 4);

  gemm_bt<0><<<dim3(3 * C_ / 128, M_ / 128), 256, 0, stream>>>(
      xb, wqkvb, b_qkv, C_, q, kk, vt, nullptr);

  // 4 waves x (32 low + 32 high) rows = 256 rows per block -> 512 blocks.
  attn_k<<<B_ * H_ * T_ / 256, 256, 0, stream>>>(q, kk, vt, ao);

  gemm_bt<1><<<dim3(C_ / 128, M_ / 128), 256, 0, stream>>>(
      ao, woutb, b_out, C_, nullptr, nullptr, nullptr, out);
}

// Round 20
// 170.166 us; speedup vs baseline: 1.1049x; 1.0085x over previous
//
#include <hip/hip_runtime.h>
#include <hip/hip_bf16.h>

// CausalSelfAttention: x[4,2048,1024] -> qkv proj -> 16-head causal attn -> out proj
// Pipeline: cvt3 -> gemm_bt<QKV> (counted vmcnt, XOR swizzle, LDS-transposed
// V epilogue) -> attn (paired bands, KVBLK=128, defer-max, compiler-scheduled
// P path) -> gemm_bt<OUT>

#define B_ 4
#define T_ 2048
#define C_ 1024
#define H_ 16
#define D_ 64
#define M_ (B_*T_)   // 8192 tokens

#define SCALE_LOG2 0.18033688f   // (1/sqrt(64)) * log2(e), folded into Q in GEMM

typedef __attribute__((ext_vector_type(8))) short short8;
typedef __attribute__((ext_vector_type(4))) float f32x4;
typedef __attribute__((ext_vector_type(16))) float f32x16;

static __device__ __forceinline__ ushort f2bf(float f) {
  __hip_bfloat16 b = __float2bfloat16(f);
  ushort u; __builtin_memcpy(&u, &b, 2); return u;
}

static __device__ __forceinline__ void ld16(const void* g, void* l) {
  __builtin_amdgcn_global_load_lds((const __attribute__((address_space(1))) void*)g,
                                   (__attribute__((address_space(3))) void*)l, 16, 0, 0);
}

static __device__ __forceinline__ f32x4 mfma16(short8 a, short8 b, f32x4 c) {
  return __builtin_amdgcn_mfma_f32_16x16x32_bf16(a, b, c, 0, 0, 0);
}
static __device__ __forceinline__ f32x16 mfma32(short8 a, short8 b, f32x16 c) {
  return __builtin_amdgcn_mfma_f32_32x32x16_bf16(a, b, c, 0, 0, 0);
}

static __device__ __forceinline__ float pair_max(float x) {
  return fmaxf(x, __shfl_xor(x, 32));
}
static __device__ __forceinline__ float pair_sum(float x) {
  return x + __shfl_xor(x, 32);
}

// ---------------- fp32 -> bf16 convert, all three tensors in one launch ----
__global__ void cvt3(const float* __restrict__ a, const float* __restrict__ b,
                     const float* __restrict__ c, ushort* __restrict__ oa,
                     ushort* __restrict__ ob, ushort* __restrict__ oc,
                     int na, int nb, int nc) {
  int tot = na + nb + nc;
  int i = blockIdx.x * blockDim.x + threadIdx.x;
  int st = gridDim.x * blockDim.x;
  for (; i < tot; i += st) {
    const float* s; ushort* d; int k = i;
    if (k < na)            { s = a; d = oa; }
    else if (k < na + nb)  { k -= na; s = b; d = ob; }
    else                   { k -= na + nb; s = c; d = oc; }
    float4 v = ((const float4*)s)[k];
    ushort4 o;
    o.x = f2bf(v.x); o.y = f2bf(v.y); o.z = f2bf(v.z); o.w = f2bf(v.w);
    ((ushort4*)d)[k] = o;
  }
}

// ---------------- C = A @ B^T + bias (both A,B K-major bf16) ----------------
// Counted-vmcnt dbuf pipeline + granule-XOR swizzle (0 conflicts). MODE 0:
// QKV -> q (pre-scaled exp2 domain), k, vt[B,H,D,T]; V-third blocks route the
// epilogue through an LDS transpose (stride-136) for coalesced-along-t stores.
// MODE 1: out projection -> fp32 d_out.
template<int MODE>
__global__ __launch_bounds__(256) void gemm_bt(
    const ushort* __restrict__ A, const ushort* __restrict__ Bm,
    const float* __restrict__ bias, int K,
    ushort* __restrict__ q, ushort* __restrict__ kk, ushort* __restrict__ vt,
    float* __restrict__ outF)
{
  __shared__ ushort SM[17408];
  const int tid = threadIdx.x;
  const int lane = tid & 63;
  const int w = tid >> 6;
  const int wr = w >> 1, wc = w & 1;
  const int l15 = lane & 15, lhi = lane >> 4;
  const long i0 = (long)blockIdx.y * 128;
  const long j0 = (long)blockIdx.x * 128;

  const int gsw = (lhi ^ ((l15 >> 1) & 3)) * 8;

  auto STAGE = [&](int buf, int k0) {
    int c = tid;
    int row = c >> 2, gs = (c & 3) ^ ((row >> 1) & 3);
    ld16((const char*)A  + ((i0 + row) * K + k0 + gs * 8) * 2, (char*)SM + buf*8192 + c*16);
    ld16((const char*)Bm + ((j0 + row) * K + k0 + gs * 8) * 2, (char*)SM + 16384 + buf*8192 + c*16);
    c = tid + 256;
    row = c >> 2; gs = (c & 3) ^ ((row >> 1) & 3);
    ld16((const char*)A  + ((i0 + row) * K + k0 + gs * 8) * 2, (char*)SM + buf*8192 + c*16);
    ld16((const char*)Bm + ((j0 + row) * K + k0 + gs * 8) * 2, (char*)SM + 16384 + buf*8192 + c*16);
  };

  f32x4 acc[4][4] = {};
  const int nsteps = K >> 5;

  STAGE(0, 0);
  STAGE(1, 32);
  int cur = 0;

  for (int t = 0; t < nsteps; t++) {
    if (t + 1 < nsteps) { asm volatile("s_waitcnt vmcnt(4)" ::: "memory"); }
    else                { asm volatile("s_waitcnt vmcnt(0)" ::: "memory"); }
    __builtin_amdgcn_s_barrier();
    __builtin_amdgcn_sched_barrier(0);

    short8 af[4], bf[4];
#pragma unroll
    for (int m = 0; m < 4; m++)
      af[m] = *(const short8*)&SM[cur*4096 + (wr*64 + m*16 + l15)*32 + gsw];
#pragma unroll
    for (int n = 0; n < 4; n++)
      bf[n] = *(const short8*)&SM[8192 + cur*4096 + (wc*64 + n*16 + l15)*32 + gsw];
    __builtin_amdgcn_s_setprio(1);
#pragma unroll
    for (int m = 0; m < 4; m++)
#pragma unroll
      for (int n = 0; n < 4; n++)
        acc[m][n] = mfma16(af[m], bf[n], acc[m][n]);
    __builtin_amdgcn_s_setprio(0);

    __builtin_amdgcn_s_barrier();
    __builtin_amdgcn_sched_barrier(0);
    if (t + 2 < nsteps) STAGE(cur, (t + 2) * 32);
    cur ^= 1;
  }

  if (MODE == 0 && j0 >= 2048) {
    // V block: LDS transpose epilogue (write [jl][tl] stride 136, read along t)
#pragma unroll
    for (int m = 0; m < 4; m++)
#pragma unroll
      for (int n = 0; n < 4; n++) {
        const int jl = wc*64 + n*16 + l15;
        const int tl = wr*64 + m*16 + lhi*4;
        const float bs = bias[j0 + jl];
        uint w0, w1;
        asm("v_cvt_pk_bf16_f32 %0, %1, %2" : "=v"(w0)
            : "v"(acc[m][n][0] + bs), "v"(acc[m][n][1] + bs));
        asm("v_cvt_pk_bf16_f32 %0, %1, %2" : "=v"(w1)
            : "v"(acc[m][n][2] + bs), "v"(acc[m][n][3] + bs));
        uint2 pr; pr.x = w0; pr.y = w1;
        *(uint2*)&SM[jl * 136 + tl] = pr;
      }
    __syncthreads();
    const int b = (int)(i0 >> 11);
    const int tb = (int)(i0 & 2047);
#pragma unroll
    for (int k2 = 0; k2 < 8; k2++) {
      const int chunk = k2 * 256 + tid;
      const int jl = chunk >> 4;
      const int t0 = (chunk & 15) * 8;
      uint4 pw = *(const uint4*)&SM[jl * 136 + t0];
      const int cc = (int)((j0 + jl) & 1023);
      const int h = cc >> 6, d = cc & 63;
      *(uint4*)&vt[((size_t)(b * H_ + h) * D_ + d) * T_ + tb + t0] = pw;
    }
  } else {
#pragma unroll
    for (int m = 0; m < 4; m++) {
#pragma unroll
      for (int n = 0; n < 4; n++) {
#pragma unroll
        for (int r = 0; r < 4; r++) {
          long i = i0 + wr*64 + m*16 + lhi*4 + r;
          int  j = (int)j0 + wc*64 + n*16 + l15;
          float v = acc[m][n][r] + bias[j];
          if (MODE == 0) {
            int b = (int)(i >> 11), t = (int)(i & 2047);
            int cc = j & 1023;
            int h = cc >> 6, d = cc & 63;
            long bh = (long)b * H_ + h;
            if (j < 1024)      q [(bh*T_ + t)*D_ + d] = f2bf(v * SCALE_LOG2);
            else               kk[(bh*T_ + t)*D_ + d] = f2bf(v);
          } else {
            outF[i * C_ + j] = v;
          }
        }
      }
    }
  }
}

// ------- causal flash attention, paired bands, KVBLK=128, defer-max -------
// r17 structure; the P round-trip has NO explicit lgkmcnt/sched_barrier:
// same-wave DS ops execute in order (write->read same address is safe) and
// the compiler inserts precise lgkmcnt before the read's MFMA use. This
// removes 2 full-drain stalls per chunk and lets the scheduler overlap
// band a's softmax with band b's P path.
#define PSTR 20   // u32 per q-row: 16 pairs + 4 pad

static __device__ __forceinline__ void softmax_pack32(
    f32x16& sc, float& m, float& lp, f32x16 (&o)[2],
    int q0, int kvbase, int l31, int hi, uint* __restrict__ P)
{
  float sv[16];
  const bool needmask = (kvbase + 31 > q0);
#pragma unroll
  for (int r = 0; r < 16; r++) {
    float xv = sc[r];
    if (needmask) {
      int kv = kvbase + (r & 3) + 8 * (r >> 2) + 4 * hi;
      if (kv > q0 + l31) xv = -1e30f;
    }
    sv[r] = xv;
  }
  // lane max via max3-friendly triples
  float a0 = fmaxf(fmaxf(sv[0], sv[1]), sv[2]);
  float a1 = fmaxf(fmaxf(sv[3], sv[4]), sv[5]);
  float a2 = fmaxf(fmaxf(sv[6], sv[7]), sv[8]);
  float a3 = fmaxf(fmaxf(sv[9], sv[10]), sv[11]);
  float a4 = fmaxf(fmaxf(sv[12], sv[13]), sv[14]);
  float pmax = fmaxf(fmaxf(fmaxf(a0, a1), a2), fmaxf(fmaxf(a3, a4), sv[15]));
  // defer-max: rare rescale only on significant growth
  if (__any(pmax > m + 8.0f)) {
    float rowm = pair_max(pmax);
    float nm = fmaxf(m, rowm);
    float alpha = __builtin_amdgcn_exp2f(m - nm);
    m = nm;
    lp *= alpha;
#pragma unroll
    for (int dt = 0; dt < 2; dt++)
#pragma unroll
      for (int r = 0; r < 16; r++) o[dt][r] *= alpha;
  }
  float s = 0.f;
#pragma unroll
  for (int r = 0; r < 16; r++) {
    float p = __builtin_amdgcn_exp2f(sv[r] - m);
    sv[r] = p;
    s += p;
  }
  lp += s;
  uint W[8];
#pragma unroll
  for (int r = 0; r < 8; r++)
    asm("v_cvt_pk_bf16_f32 %0, %1, %2" : "=v"(W[r]) : "v"(sv[2*r]), "v"(sv[2*r+1]));
#pragma unroll
  for (int r2 = 0; r2 < 4; r2++) {
    uint2 pr; pr.x = W[2*r2]; pr.y = W[2*r2 + 1];
    *(uint2*)&P[l31 * PSTR + r2*4 + 2*hi] = pr;
  }
}

__global__ __launch_bounds__(256, 2) void attn_k(
    const ushort* __restrict__ Q, const ushort* __restrict__ K,
    const ushort* __restrict__ V, ushort* __restrict__ AO)
{
  __shared__ ushort Kt[2][128*64];
  __shared__ ushort Vt[2][64*128];
  __shared__ uint P2[4][32 * PSTR];
  const int tid = threadIdx.x;
  const int lane = tid & 63;
  const int w = tid >> 6;              // 0..3
  const int l31 = lane & 31, hi = lane >> 5;
  const int bb = blockIdx.x;
  const int head = bb & 63;            // bb%8 = head%8 -> same-head same XCD
  const int i = bb >> 6;               // 0..7
  const int J = (i < 4) ? i : 11 - i;  // complementary pairing bb, bb+256
  const int nst = 16 - J;              // 128-kv tiles (>= 9)
  const int q0a = 128 * J + 32 * w;            // low band
  const int q0b = 2016 - 128 * J - 32 * w;     // high (mirror) band

  const ushort* Qb = Q + (size_t)head * T_ * D_;
  const ushort* Kb = K + (size_t)head * T_ * D_;
  const ushort* Vb = V + (size_t)head * D_ * T_;   // [d][t]

  auto STAGE = [&](int buf, int kv0s) {
#pragma unroll
    for (int hb = 0; hb < 4; hb++) {
      int slot = tid + hb * 256;            // 0..1023
      int krow = slot >> 3, kg = slot & 7, kgs = kg ^ (krow & 7);
      ld16((const char*)Kb + ((size_t)(kv0s + krow) * D_ + kgs * 8) * 2,
           (char*)&Kt[buf][0] + slot * 16);
      int vrow = slot >> 4, vg = slot & 15, vgs = vg ^ (vrow & 15);
      ld16((const char*)Vb + ((size_t)vrow * T_ + kv0s + vgs * 8) * 2,
           (char*)&Vt[buf][0] + slot * 16);
    }
  };

  // Q as B-fragment: lane holds Q[q0+l31][d = s*16 + hi*8 + e] per slice s.
  short8 qfa[4], qfb[4];
#pragma unroll
  for (int s = 0; s < 4; s++) {
    qfa[s] = *(const short8*)&Qb[(q0a + l31) * D_ + s*16 + hi*8];
    qfb[s] = *(const short8*)&Qb[(q0b + l31) * D_ + s*16 + hi*8];
  }

  f32x16 oa[2] = {}, ob[2] = {};       // O'[d][q]: d = dt*32 + (r&3)+8(r>>2)+4hi
  float ma = -1e30f, la = 0.f, mb = -1e30f, lb = 0.f;

  STAGE(0, 0);
  STAGE(1, 128);
  int cur = 0;
  uint* P = &P2[w][0];

  for (int t = 0; t < nst; t++) {
    const int kv0 = t * 128;
    if (t + 1 < nst) { asm volatile("s_waitcnt vmcnt(8)" ::: "memory"); }
    else             { asm volatile("s_waitcnt vmcnt(0)" ::: "memory"); }
    __builtin_amdgcn_s_barrier();
    __builtin_amdgcn_sched_barrier(0);

#pragma unroll
    for (int c = 0; c < 4; c++) {
      const int kvc = kv0 + 32 * c;
      const bool act_b = (kvc <= q0b + 31);
      const bool act_a = (kvc <= q0a + 31);   // act_a implies act_b
      if (act_b) {
        // K A-fragment: lane holds K[c*32+l31][d = s*16 + hi*8 + e]
        short8 kf[4];
#pragma unroll
        for (int s = 0; s < 4; s++) {
          const int row = c*32 + l31;
          kf[s] = *(const short8*)&Kt[cur][row*64 + (((2*s + hi) ^ (row & 7)) << 3)];
        }
        // Vt A-fragment: Vt[dt*32+l31][kv = c*32 + sl*16 + hi*8 + e]
        short8 vf[2][2];
#pragma unroll
        for (int sl = 0; sl < 2; sl++)
#pragma unroll
          for (int dt = 0; dt < 2; dt++) {
            const int row = dt*32 + l31;
            const int u = c*4 + sl*2 + hi;
            vf[sl][dt] = *(const short8*)
                &Vt[cur][row*128 + ((u ^ (row & 15)) << 3)];
          }

        // ---- band b ----
        {
          f32x16 scb = {};
          __builtin_amdgcn_s_setprio(1);
#pragma unroll
          for (int s = 0; s < 4; s++) scb = mfma32(kf[s], qfb[s], scb);
          __builtin_amdgcn_s_setprio(0);
          softmax_pack32(scb, mb, lb, ob, q0b, kvc, l31, hi, P);
          // no explicit wait: same-wave DS in-order; compiler guards read->use
          short8 pf[2];
#pragma unroll
          for (int sl = 0; sl < 2; sl++) {
            uint4 pw = *(const uint4*)&P[l31 * PSTR + sl*8 + hi*4];
            __builtin_memcpy(&pf[sl], &pw, 16);
          }
          __builtin_amdgcn_s_setprio(1);
#pragma unroll
          for (int sl = 0; sl < 2; sl++)
#pragma unroll
            for (int dt = 0; dt < 2; dt++)
              ob[dt] = mfma32(vf[sl][dt], pf[sl], ob[dt]);
          __builtin_amdgcn_s_setprio(0);
        }
        // ---- band a (reuses kf, vf; P writes ordered after b's reads) ----
        if (act_a) {
          f32x16 sca = {};
          __builtin_amdgcn_s_setprio(1);
#pragma unroll
          for (int s = 0; s < 4; s++) sca = mfma32(kf[s], qfa[s], sca);
          __builtin_amdgcn_s_setprio(0);
          softmax_pack32(sca, ma, la, oa, q0a, kvc, l31, hi, P);
          short8 pf[2];
#pragma unroll
          for (int sl = 0; sl < 2; sl++) {
            uint4 pw = *(const uint4*)&P[l31 * PSTR + sl*8 + hi*4];
            __builtin_memcpy(&pf[sl], &pw, 16);
          }
          __builtin_amdgcn_s_setprio(1);
#pragma unroll
          for (int sl = 0; sl < 2; sl++)
#pragma unroll
            for (int dt = 0; dt < 2; dt++)
              oa[dt] = mfma32(vf[sl][dt], pf[sl], oa[dt]);
          __builtin_amdgcn_s_setprio(0);
        }
      }
    }

    __builtin_amdgcn_s_barrier();
    __builtin_amdgcn_sched_barrier(0);
    if (t + 2 < nst) STAGE(cur, kv0 + 256);   // overwrite freed buffer
    cur ^= 1;
  }

  const int b = head >> 4, h = head & 15;
  {
    const float invl = 1.0f / pair_sum(lb);
    const size_t rowb = (size_t)(b * T_ + q0b + l31) * C_ + h * 64;
#pragma unroll
    for (int dt = 0; dt < 2; dt++)
#pragma unroll
      for (int rg = 0; rg < 4; rg++) {
        const int d0 = dt*32 + 8*rg + 4*hi;
        ushort4 ov;
        ov.x = f2bf(ob[dt][rg*4+0] * invl);
        ov.y = f2bf(ob[dt][rg*4+1] * invl);
        ov.z = f2bf(ob[dt][rg*4+2] * invl);
        ov.w = f2bf(ob[dt][rg*4+3] * invl);
        *(ushort4*)&AO[rowb + d0] = ov;
      }
  }
  {
    const float invl = 1.0f / pair_sum(la);
    const size_t rowb = (size_t)(b * T_ + q0a + l31) * C_ + h * 64;
#pragma unroll
    for (int dt = 0; dt < 2; dt++)
#pragma unroll
      for (int rg = 0; rg < 4; rg++) {
        const int d0 = dt*32 + 8*rg + 4*hi;
        ushort4 ov;
        ov.x = f2bf(oa[dt][rg*4+0] * invl);
        ov.y = f2bf(oa[dt][rg*4+1] * invl);
        ov.z = f2bf(oa[dt][rg*4+2] * invl);
        ov.w = f2bf(oa[dt][rg*4+3] * invl);
        *(ushort4*)&AO[rowb + d0] = ov;
      }
  }
}

extern "C" void kernel_launch(void* const* d_in, const int* in_sizes, int n_in,
                              void* d_out, int out_size, void* d_ws, size_t ws_size,
                              hipStream_t stream) {
  const float* x     = (const float*)d_in[0];
  const float* w_qkv = (const float*)d_in[1];
  const float* b_qkv = (const float*)d_in[2];
  const float* w_out = (const float*)d_in[3];
  const float* b_out = (const float*)d_in[4];
  float* out = (float*)d_out;

  ushort* xb    = (ushort*)d_ws;                    // 8192*1024
  ushort* wqkvb = xb    + (size_t)M_ * C_;          // 3072*1024
  ushort* woutb = wqkvb + (size_t)3 * C_ * C_;      // 1024*1024
  ushort* q     = woutb + (size_t)C_ * C_;          // [B,H,T,D] (exp2-domain scaled)
  ushort* kk    = q     + (size_t)M_ * C_;          // [B,H,T,D]
  ushort* vt    = kk    + (size_t)M_ * C_;          // [B,H,D,T]
  ushort* ao    = xb;                               // reuse xb (free after QKV GEMM)

  cvt3<<<2048, 256, 0, stream>>>(x, w_qkv, w_out, xb, wqkvb, woutb,
                                 (M_ * C_) / 4, (3 * C_ * C_) / 4, (C_ * C_) / 4);

  gemm_bt<0><<<dim3(3 * C_ / 128, M_ / 128), 256, 0, stream>>>(
      xb, wqkvb, b_qkv, C_, q, kk, vt, nullptr);

  // 4 waves x (32 low + 32 high) rows = 256 rows per block -> 512 blocks.
  attn_k<<<B_ * H_ * T_ / 256, 256, 0, stream>>>(q, kk, vt, ao);

  gemm_bt<1><<<dim3(C_ / 128, M_ / 128), 256, 0, stream>>>(
      ao, woutb, b_out, C_, nullptr, nullptr, nullptr, out);
}

// Round 22
// 169.171 us; speedup vs baseline: 1.1114x; 1.0059x over previous
//
#include <hip/hip_runtime.h>
#include <hip/hip_bf16.h>

// CausalSelfAttention: x[4,2048,1024] -> qkv proj -> 16-head causal attn -> out proj
// Pipeline: cvt3 -> gemm_bt<QKV> (counted vmcnt, XOR swizzle, LDS-transposed
// V epilogue) -> attn (single-band waves, KVBLK=64, LDS-P relayout, 3 blk/CU)
// -> gemm_bt<OUT>

#define B_ 4
#define T_ 2048
#define C_ 1024
#define H_ 16
#define D_ 64
#define M_ (B_*T_)   // 8192 tokens

#define SCALE_LOG2 0.18033688f   // (1/sqrt(64)) * log2(e), folded into Q in GEMM

typedef __attribute__((ext_vector_type(8))) short short8;
typedef __attribute__((ext_vector_type(4))) float f32x4;
typedef __attribute__((ext_vector_type(16))) float f32x16;

static __device__ __forceinline__ ushort f2bf(float f) {
  __hip_bfloat16 b = __float2bfloat16(f);
  ushort u; __builtin_memcpy(&u, &b, 2); return u;
}

static __device__ __forceinline__ void ld16(const void* g, void* l) {
  __builtin_amdgcn_global_load_lds((const __attribute__((address_space(1))) void*)g,
                                   (__attribute__((address_space(3))) void*)l, 16, 0, 0);
}

static __device__ __forceinline__ f32x4 mfma16(short8 a, short8 b, f32x4 c) {
  return __builtin_amdgcn_mfma_f32_16x16x32_bf16(a, b, c, 0, 0, 0);
}
static __device__ __forceinline__ f32x16 mfma32(short8 a, short8 b, f32x16 c) {
  return __builtin_amdgcn_mfma_f32_32x32x16_bf16(a, b, c, 0, 0, 0);
}

static __device__ __forceinline__ float pair_max(float x) {
  return fmaxf(x, __shfl_xor(x, 32));
}
static __device__ __forceinline__ float pair_sum(float x) {
  return x + __shfl_xor(x, 32);
}

// ---------------- fp32 -> bf16 convert, all three tensors in one launch ----
__global__ void cvt3(const float* __restrict__ a, const float* __restrict__ b,
                     const float* __restrict__ c, ushort* __restrict__ oa,
                     ushort* __restrict__ ob, ushort* __restrict__ oc,
                     int na, int nb, int nc) {
  int tot = na + nb + nc;
  int i = blockIdx.x * blockDim.x + threadIdx.x;
  int st = gridDim.x * blockDim.x;
  for (; i < tot; i += st) {
    const float* s; ushort* d; int k = i;
    if (k < na)            { s = a; d = oa; }
    else if (k < na + nb)  { k -= na; s = b; d = ob; }
    else                   { k -= na + nb; s = c; d = oc; }
    float4 v = ((const float4*)s)[k];
    ushort4 o;
    o.x = f2bf(v.x); o.y = f2bf(v.y); o.z = f2bf(v.z); o.w = f2bf(v.w);
    ((ushort4*)d)[k] = o;
  }
}

// ---------------- C = A @ B^T + bias (both A,B K-major bf16) ----------------
// Counted-vmcnt dbuf pipeline + granule-XOR swizzle (0 conflicts). MODE 0:
// QKV -> q (pre-scaled exp2 domain), k, vt[B,H,D,T]; V-third blocks route the
// epilogue through an LDS transpose (stride-136) for coalesced-along-t stores.
// MODE 1: out projection -> fp32 d_out.
template<int MODE>
__global__ __launch_bounds__(256) void gemm_bt(
    const ushort* __restrict__ A, const ushort* __restrict__ Bm,
    const float* __restrict__ bias, int K,
    ushort* __restrict__ q, ushort* __restrict__ kk, ushort* __restrict__ vt,
    float* __restrict__ outF)
{
  __shared__ ushort SM[17408];
  const int tid = threadIdx.x;
  const int lane = tid & 63;
  const int w = tid >> 6;
  const int wr = w >> 1, wc = w & 1;
  const int l15 = lane & 15, lhi = lane >> 4;
  const long i0 = (long)blockIdx.y * 128;
  const long j0 = (long)blockIdx.x * 128;

  const int gsw = (lhi ^ ((l15 >> 1) & 3)) * 8;

  auto STAGE = [&](int buf, int k0) {
    int c = tid;
    int row = c >> 2, gs = (c & 3) ^ ((row >> 1) & 3);
    ld16((const char*)A  + ((i0 + row) * K + k0 + gs * 8) * 2, (char*)SM + buf*8192 + c*16);
    ld16((const char*)Bm + ((j0 + row) * K + k0 + gs * 8) * 2, (char*)SM + 16384 + buf*8192 + c*16);
    c = tid + 256;
    row = c >> 2; gs = (c & 3) ^ ((row >> 1) & 3);
    ld16((const char*)A  + ((i0 + row) * K + k0 + gs * 8) * 2, (char*)SM + buf*8192 + c*16);
    ld16((const char*)Bm + ((j0 + row) * K + k0 + gs * 8) * 2, (char*)SM + 16384 + buf*8192 + c*16);
  };

  f32x4 acc[4][4] = {};
  const int nsteps = K >> 5;

  STAGE(0, 0);
  STAGE(1, 32);
  int cur = 0;

  for (int t = 0; t < nsteps; t++) {
    if (t + 1 < nsteps) { asm volatile("s_waitcnt vmcnt(4)" ::: "memory"); }
    else                { asm volatile("s_waitcnt vmcnt(0)" ::: "memory"); }
    __builtin_amdgcn_s_barrier();
    __builtin_amdgcn_sched_barrier(0);

    short8 af[4], bf[4];
#pragma unroll
    for (int m = 0; m < 4; m++)
      af[m] = *(const short8*)&SM[cur*4096 + (wr*64 + m*16 + l15)*32 + gsw];
#pragma unroll
    for (int n = 0; n < 4; n++)
      bf[n] = *(const short8*)&SM[8192 + cur*4096 + (wc*64 + n*16 + l15)*32 + gsw];
    __builtin_amdgcn_s_setprio(1);
#pragma unroll
    for (int m = 0; m < 4; m++)
#pragma unroll
      for (int n = 0; n < 4; n++)
        acc[m][n] = mfma16(af[m], bf[n], acc[m][n]);
    __builtin_amdgcn_s_setprio(0);

    __builtin_amdgcn_s_barrier();
    __builtin_amdgcn_sched_barrier(0);
    if (t + 2 < nsteps) STAGE(cur, (t + 2) * 32);
    cur ^= 1;
  }

  if (MODE == 0 && j0 >= 2048) {
    // V block: LDS transpose epilogue (write [jl][tl] stride 136, read along t)
#pragma unroll
    for (int m = 0; m < 4; m++)
#pragma unroll
      for (int n = 0; n < 4; n++) {
        const int jl = wc*64 + n*16 + l15;
        const int tl = wr*64 + m*16 + lhi*4;
        const float bs = bias[j0 + jl];
        uint w0, w1;
        asm("v_cvt_pk_bf16_f32 %0, %1, %2" : "=v"(w0)
            : "v"(acc[m][n][0] + bs), "v"(acc[m][n][1] + bs));
        asm("v_cvt_pk_bf16_f32 %0, %1, %2" : "=v"(w1)
            : "v"(acc[m][n][2] + bs), "v"(acc[m][n][3] + bs));
        uint2 pr; pr.x = w0; pr.y = w1;
        *(uint2*)&SM[jl * 136 + tl] = pr;
      }
    __syncthreads();
    const int b = (int)(i0 >> 11);
    const int tb = (int)(i0 & 2047);
#pragma unroll
    for (int k2 = 0; k2 < 8; k2++) {
      const int chunk = k2 * 256 + tid;
      const int jl = chunk >> 4;
      const int t0 = (chunk & 15) * 8;
      uint4 pw = *(const uint4*)&SM[jl * 136 + t0];
      const int cc = (int)((j0 + jl) & 1023);
      const int h = cc >> 6, d = cc & 63;
      *(uint4*)&vt[((size_t)(b * H_ + h) * D_ + d) * T_ + tb + t0] = pw;
    }
  } else {
#pragma unroll
    for (int m = 0; m < 4; m++) {
#pragma unroll
      for (int n = 0; n < 4; n++) {
#pragma unroll
        for (int r = 0; r < 4; r++) {
          long i = i0 + wr*64 + m*16 + lhi*4 + r;
          int  j = (int)j0 + wc*64 + n*16 + l15;
          float v = acc[m][n][r] + bias[j];
          if (MODE == 0) {
            int b = (int)(i >> 11), t = (int)(i & 2047);
            int cc = j & 1023;
            int h = cc >> 6, d = cc & 63;
            long bh = (long)b * H_ + h;
            if (j < 1024)      q [(bh*T_ + t)*D_ + d] = f2bf(v * SCALE_LOG2);
            else               kk[(bh*T_ + t)*D_ + d] = f2bf(v);
          } else {
            outF[i * C_ + j] = v;
          }
        }
      }
    }
  }
}

// ---- causal flash attention, single-band waves, KVBLK=64, LDS-P relayout ----
// 1024 blocks x 256 threads (4 waves). head = bb&63 (8 heads/XCD), rblk =
// 15-(bb>>6) (longest-first; backfill keeps the machine packed). Wave w owns
// rows [128*rblk + 32w, +31]; nst = 2*rblk+2 tiles of 64 kv.
// K[64][64] + Vt[64][64] double-buffered (counted vmcnt(4), XOR granule
// swizzle) + P2 = 43KB LDS; launch_bounds(256,3) -> 3 blocks/CU (12 waves/CU
// vs 8 for the paired variant). Per 32-kv chunk: QK=mfma32(K,Q); defer-max
// softmax (lane-partial l); P via the r12-proven wave-private LDS relayout
// (compiler-scheduled, no explicit waits per r20); PV=mfma32(Vt,P).
#define PSTR 20   // u32 per q-row: 16 pairs + 4 pad

static __device__ __forceinline__ void softmax_pack32(
    f32x16& sc, float& m, float& lp, f32x16 (&o)[2],
    int q0, int kvbase, int l31, int hi, uint* __restrict__ P)
{
  float sv[16];
  const bool needmask = (kvbase + 31 > q0);
#pragma unroll
  for (int r = 0; r < 16; r++) {
    float xv = sc[r];
    if (needmask) {
      int kv = kvbase + (r & 3) + 8 * (r >> 2) + 4 * hi;
      if (kv > q0 + l31) xv = -1e30f;
    }
    sv[r] = xv;
  }
  float a0 = fmaxf(fmaxf(sv[0], sv[1]), sv[2]);
  float a1 = fmaxf(fmaxf(sv[3], sv[4]), sv[5]);
  float a2 = fmaxf(fmaxf(sv[6], sv[7]), sv[8]);
  float a3 = fmaxf(fmaxf(sv[9], sv[10]), sv[11]);
  float a4 = fmaxf(fmaxf(sv[12], sv[13]), sv[14]);
  float pmax = fmaxf(fmaxf(fmaxf(a0, a1), a2), fmaxf(fmaxf(a3, a4), sv[15]));
  if (__any(pmax > m + 8.0f)) {        // rare rescale
    float rowm = pair_max(pmax);
    float nm = fmaxf(m, rowm);
    float alpha = __builtin_amdgcn_exp2f(m - nm);
    m = nm;
    lp *= alpha;
#pragma unroll
    for (int dt = 0; dt < 2; dt++)
#pragma unroll
      for (int r = 0; r < 16; r++) o[dt][r] *= alpha;
  }
  float s = 0.f;
#pragma unroll
  for (int r = 0; r < 16; r++) {
    float p = __builtin_amdgcn_exp2f(sv[r] - m);
    sv[r] = p;
    s += p;
  }
  lp += s;
  uint W[8];
#pragma unroll
  for (int r = 0; r < 8; r++)
    asm("v_cvt_pk_bf16_f32 %0, %1, %2" : "=v"(W[r]) : "v"(sv[2*r]), "v"(sv[2*r+1]));
#pragma unroll
  for (int r2 = 0; r2 < 4; r2++) {
    uint2 pr; pr.x = W[2*r2]; pr.y = W[2*r2 + 1];
    *(uint2*)&P[l31 * PSTR + r2*4 + 2*hi] = pr;
  }
}

__global__ __launch_bounds__(256, 3) void attn_k(
    const ushort* __restrict__ Q, const ushort* __restrict__ K,
    const ushort* __restrict__ V, ushort* __restrict__ AO)
{
  __shared__ ushort Kt[2][64*64];
  __shared__ ushort Vt[2][64*64];
  __shared__ uint P2[4][32 * PSTR];
  const int tid = threadIdx.x;
  const int lane = tid & 63;
  const int w = tid >> 6;              // 0..3
  const int l31 = lane & 31, hi = lane >> 5;
  const int bb = blockIdx.x;
  const int head = bb & 63;            // bb%8 = head%8 -> same-head same XCD
  const int rblk = 15 - (bb >> 6);     // longest-first launch order
  const int nst = 2 * rblk + 2;        // 64-kv tiles
  const int q0 = 128 * rblk + 32 * w;

  const ushort* Qb = Q + (size_t)head * T_ * D_;
  const ushort* Kb = K + (size_t)head * T_ * D_;
  const ushort* Vb = V + (size_t)head * D_ * T_;   // [d][t]

  auto STAGE = [&](int buf, int kv0s) {
#pragma unroll
    for (int hb = 0; hb < 2; hb++) {
      int slot = tid + hb * 256;            // 0..511
      int row = slot >> 3, g = slot & 7, gs = g ^ (row & 7);
      ld16((const char*)Kb + ((size_t)(kv0s + row) * D_ + gs * 8) * 2,
           (char*)&Kt[buf][0] + slot * 16);
      ld16((const char*)Vb + ((size_t)row * T_ + kv0s + gs * 8) * 2,
           (char*)&Vt[buf][0] + slot * 16);
    }
  };

  // Q as B-fragment: lane holds Q[q0+l31][d = s*16 + hi*8 + e] per slice s.
  short8 qf[4];
#pragma unroll
  for (int s = 0; s < 4; s++)
    qf[s] = *(const short8*)&Qb[(q0 + l31) * D_ + s*16 + hi*8];

  f32x16 o[2] = {};          // O'[d][q]: d = dt*32 + (r&3)+8(r>>2)+4hi, q=l31
  float m = -1e30f, lp = 0.f;

  STAGE(0, 0);
  STAGE(1, 64);              // nst >= 2 always
  int cur = 0;
  uint* P = &P2[w][0];

  for (int t = 0; t < nst; t++) {
    const int kv0 = t * 64;
    if (t + 1 < nst) { asm volatile("s_waitcnt vmcnt(4)" ::: "memory"); }
    else             { asm volatile("s_waitcnt vmcnt(0)" ::: "memory"); }
    __builtin_amdgcn_s_barrier();
    __builtin_amdgcn_sched_barrier(0);

#pragma unroll
    for (int c = 0; c < 2; c++) {
      const int kvc = kv0 + 32 * c;
      if (kvc <= q0 + 31) {
        // K A-fragment: lane holds K[c*32+l31][d = s*16 + hi*8 + e]
        short8 kf[4];
#pragma unroll
        for (int s = 0; s < 4; s++) {
          const int row = c*32 + l31;
          kf[s] = *(const short8*)&Kt[cur][row*64 + (((2*s + hi) ^ (row & 7)) << 3)];
        }
        // Vt A-fragment: Vt[dt*32+l31][kv = c*32 + sl*16 + hi*8 + e]
        short8 vf[2][2];
#pragma unroll
        for (int sl = 0; sl < 2; sl++)
#pragma unroll
          for (int dt = 0; dt < 2; dt++) {
            const int row = dt*32 + l31;
            const int u = c*4 + sl*2 + hi;
            vf[sl][dt] = *(const short8*)&Vt[cur][row*64 + ((u ^ (row & 7)) << 3)];
          }

        f32x16 sc = {};
        __builtin_amdgcn_s_setprio(1);
#pragma unroll
        for (int s = 0; s < 4; s++) sc = mfma32(kf[s], qf[s], sc);
        __builtin_amdgcn_s_setprio(0);

        softmax_pack32(sc, m, lp, o, q0, kvc, l31, hi, P);
        // no explicit wait: same-wave DS in-order; compiler guards read->use
        short8 pf[2];
#pragma unroll
        for (int sl = 0; sl < 2; sl++) {
          uint4 pw = *(const uint4*)&P[l31 * PSTR + sl*8 + hi*4];
          __builtin_memcpy(&pf[sl], &pw, 16);
        }
        __builtin_amdgcn_s_setprio(1);
#pragma unroll
        for (int dt = 0; dt < 2; dt++) {
          o[dt] = mfma32(vf[0][dt], pf[0], o[dt]);
          o[dt] = mfma32(vf[1][dt], pf[1], o[dt]);
        }
        __builtin_amdgcn_s_setprio(0);
      }
    }

    __builtin_amdgcn_s_barrier();
    __builtin_amdgcn_sched_barrier(0);
    if (t + 2 < nst) STAGE(cur, kv0 + 128);   // overwrite freed buffer
    cur ^= 1;
  }

  const int b = head >> 4, h = head & 15;
  const float invl = 1.0f / pair_sum(lp);
  const size_t rowb = (size_t)(b * T_ + q0 + l31) * C_ + h * 64;
#pragma unroll
  for (int dt = 0; dt < 2; dt++)
#pragma unroll
    for (int rg = 0; rg < 4; rg++) {
      const int d0 = dt*32 + 8*rg + 4*hi;
      ushort4 ov;
      ov.x = f2bf(o[dt][rg*4+0] * invl);
      ov.y = f2bf(o[dt][rg*4+1] * invl);
      ov.z = f2bf(o[dt][rg*4+2] * invl);
      ov.w = f2bf(o[dt][rg*4+3] * invl);
      *(ushort4*)&AO[rowb + d0] = ov;
    }
}

extern "C" void kernel_launch(void* const* d_in, const int* in_sizes, int n_in,
                              void* d_out, int out_size, void* d_ws, size_t ws_size,
                              hipStream_t stream) {
  const float* x     = (const float*)d_in[0];
  const float* w_qkv = (const float*)d_in[1];
  const float* b_qkv = (const float*)d_in[2];
  const float* w_out = (const float*)d_in[3];
  const float* b_out = (const float*)d_in[4];
  float* out = (float*)d_out;

  ushort* xb    = (ushort*)d_ws;                    // 8192*1024
  ushort* wqkvb = xb    + (size_t)M_ * C_;          // 3072*1024
  ushort* woutb = wqkvb + (size_t)3 * C_ * C_;      // 1024*1024
  ushort* q     = woutb + (size_t)C_ * C_;          // [B,H,T,D] (exp2-domain scaled)
  ushort* kk    = q     + (size_t)M_ * C_;          // [B,H,T,D]
  ushort* vt    = kk    + (size_t)M_ * C_;          // [B,H,D,T]
  ushort* ao    = xb;                               // reuse xb (free after QKV GEMM)

  cvt3<<<2048, 256, 0, stream>>>(x, w_qkv, w_out, xb, wqkvb, woutb,
                                 (M_ * C_) / 4, (3 * C_ * C_) / 4, (C_ * C_) / 4);

  gemm_bt<0><<<dim3(3 * C_ / 128, M_ / 128), 256, 0, stream>>>(
      xb, wqkvb, b_qkv, C_, q, kk, vt, nullptr);

  // 4 waves x 32 rows = 128 rows per block, one band -> 1024 blocks.
  attn_k<<<B_ * H_ * T_ / 128, 256, 0, stream>>>(q, kk, vt, ao);

  gemm_bt<1><<<dim3(C_ / 128, M_ / 128), 256, 0, stream>>>(
      ao, woutb, b_out, C_, nullptr, nullptr, nullptr, out);
}

// Round 23
// 168.765 us; speedup vs baseline: 1.1141x; 1.0024x over previous
//
#include <hip/hip_runtime.h>
#include <hip/hip_bf16.h>

// CausalSelfAttention: x[4,2048,1024] -> qkv proj -> 16-head causal attn -> out proj
// Pipeline: cvt3 -> gemm_bt<QKV> (counted vmcnt, XOR swizzle, LDS-transposed
// V epilogue) -> attn (single-band waves, KVBLK=64, both-chunk QK upfront,
// LDS-P relayout, 3 blk/CU) -> gemm_bt<OUT>

#define B_ 4
#define T_ 2048
#define C_ 1024
#define H_ 16
#define D_ 64
#define M_ (B_*T_)   // 8192 tokens

#define SCALE_LOG2 0.18033688f   // (1/sqrt(64)) * log2(e), folded into Q in GEMM

typedef __attribute__((ext_vector_type(8))) short short8;
typedef __attribute__((ext_vector_type(4))) float f32x4;
typedef __attribute__((ext_vector_type(16))) float f32x16;

static __device__ __forceinline__ ushort f2bf(float f) {
  __hip_bfloat16 b = __float2bfloat16(f);
  ushort u; __builtin_memcpy(&u, &b, 2); return u;
}

static __device__ __forceinline__ void ld16(const void* g, void* l) {
  __builtin_amdgcn_global_load_lds((const __attribute__((address_space(1))) void*)g,
                                   (__attribute__((address_space(3))) void*)l, 16, 0, 0);
}

static __device__ __forceinline__ f32x4 mfma16(short8 a, short8 b, f32x4 c) {
  return __builtin_amdgcn_mfma_f32_16x16x32_bf16(a, b, c, 0, 0, 0);
}
static __device__ __forceinline__ f32x16 mfma32(short8 a, short8 b, f32x16 c) {
  return __builtin_amdgcn_mfma_f32_32x32x16_bf16(a, b, c, 0, 0, 0);
}

static __device__ __forceinline__ float pair_max(float x) {
  return fmaxf(x, __shfl_xor(x, 32));
}
static __device__ __forceinline__ float pair_sum(float x) {
  return x + __shfl_xor(x, 32);
}

// ---------------- fp32 -> bf16 convert, all three tensors in one launch ----
__global__ void cvt3(const float* __restrict__ a, const float* __restrict__ b,
                     const float* __restrict__ c, ushort* __restrict__ oa,
                     ushort* __restrict__ ob, ushort* __restrict__ oc,
                     int na, int nb, int nc) {
  int tot = na + nb + nc;
  int i = blockIdx.x * blockDim.x + threadIdx.x;
  int st = gridDim.x * blockDim.x;
  for (; i < tot; i += st) {
    const float* s; ushort* d; int k = i;
    if (k < na)            { s = a; d = oa; }
    else if (k < na + nb)  { k -= na; s = b; d = ob; }
    else                   { k -= na + nb; s = c; d = oc; }
    float4 v = ((const float4*)s)[k];
    ushort4 o;
    o.x = f2bf(v.x); o.y = f2bf(v.y); o.z = f2bf(v.z); o.w = f2bf(v.w);
    ((ushort4*)d)[k] = o;
  }
}

// ---------------- C = A @ B^T + bias (both A,B K-major bf16) ----------------
// Counted-vmcnt dbuf pipeline + granule-XOR swizzle (0 conflicts). MODE 0:
// QKV -> q (pre-scaled exp2 domain), k, vt[B,H,D,T]; V-third blocks route the
// epilogue through an LDS transpose (stride-136) for coalesced-along-t stores.
// MODE 1: out projection -> fp32 d_out.
template<int MODE>
__global__ __launch_bounds__(256) void gemm_bt(
    const ushort* __restrict__ A, const ushort* __restrict__ Bm,
    const float* __restrict__ bias, int K,
    ushort* __restrict__ q, ushort* __restrict__ kk, ushort* __restrict__ vt,
    float* __restrict__ outF)
{
  __shared__ ushort SM[17408];
  const int tid = threadIdx.x;
  const int lane = tid & 63;
  const int w = tid >> 6;
  const int wr = w >> 1, wc = w & 1;
  const int l15 = lane & 15, lhi = lane >> 4;
  const long i0 = (long)blockIdx.y * 128;
  const long j0 = (long)blockIdx.x * 128;

  const int gsw = (lhi ^ ((l15 >> 1) & 3)) * 8;

  auto STAGE = [&](int buf, int k0) {
    int c = tid;
    int row = c >> 2, gs = (c & 3) ^ ((row >> 1) & 3);
    ld16((const char*)A  + ((i0 + row) * K + k0 + gs * 8) * 2, (char*)SM + buf*8192 + c*16);
    ld16((const char*)Bm + ((j0 + row) * K + k0 + gs * 8) * 2, (char*)SM + 16384 + buf*8192 + c*16);
    c = tid + 256;
    row = c >> 2; gs = (c & 3) ^ ((row >> 1) & 3);
    ld16((const char*)A  + ((i0 + row) * K + k0 + gs * 8) * 2, (char*)SM + buf*8192 + c*16);
    ld16((const char*)Bm + ((j0 + row) * K + k0 + gs * 8) * 2, (char*)SM + 16384 + buf*8192 + c*16);
  };

  f32x4 acc[4][4] = {};
  const int nsteps = K >> 5;

  STAGE(0, 0);
  STAGE(1, 32);
  int cur = 0;

  for (int t = 0; t < nsteps; t++) {
    if (t + 1 < nsteps) { asm volatile("s_waitcnt vmcnt(4)" ::: "memory"); }
    else                { asm volatile("s_waitcnt vmcnt(0)" ::: "memory"); }
    __builtin_amdgcn_s_barrier();
    __builtin_amdgcn_sched_barrier(0);

    short8 af[4], bf[4];
#pragma unroll
    for (int m = 0; m < 4; m++)
      af[m] = *(const short8*)&SM[cur*4096 + (wr*64 + m*16 + l15)*32 + gsw];
#pragma unroll
    for (int n = 0; n < 4; n++)
      bf[n] = *(const short8*)&SM[8192 + cur*4096 + (wc*64 + n*16 + l15)*32 + gsw];
    __builtin_amdgcn_s_setprio(1);
#pragma unroll
    for (int m = 0; m < 4; m++)
#pragma unroll
      for (int n = 0; n < 4; n++)
        acc[m][n] = mfma16(af[m], bf[n], acc[m][n]);
    __builtin_amdgcn_s_setprio(0);

    __builtin_amdgcn_s_barrier();
    __builtin_amdgcn_sched_barrier(0);
    if (t + 2 < nsteps) STAGE(cur, (t + 2) * 32);
    cur ^= 1;
  }

  if (MODE == 0 && j0 >= 2048) {
    // V block: LDS transpose epilogue (write [jl][tl] stride 136, read along t)
#pragma unroll
    for (int m = 0; m < 4; m++)
#pragma unroll
      for (int n = 0; n < 4; n++) {
        const int jl = wc*64 + n*16 + l15;
        const int tl = wr*64 + m*16 + lhi*4;
        const float bs = bias[j0 + jl];
        uint w0, w1;
        asm("v_cvt_pk_bf16_f32 %0, %1, %2" : "=v"(w0)
            : "v"(acc[m][n][0] + bs), "v"(acc[m][n][1] + bs));
        asm("v_cvt_pk_bf16_f32 %0, %1, %2" : "=v"(w1)
            : "v"(acc[m][n][2] + bs), "v"(acc[m][n][3] + bs));
        uint2 pr; pr.x = w0; pr.y = w1;
        *(uint2*)&SM[jl * 136 + tl] = pr;
      }
    __syncthreads();
    const int b = (int)(i0 >> 11);
    const int tb = (int)(i0 & 2047);
#pragma unroll
    for (int k2 = 0; k2 < 8; k2++) {
      const int chunk = k2 * 256 + tid;
      const int jl = chunk >> 4;
      const int t0 = (chunk & 15) * 8;
      uint4 pw = *(const uint4*)&SM[jl * 136 + t0];
      const int cc = (int)((j0 + jl) & 1023);
      const int h = cc >> 6, d = cc & 63;
      *(uint4*)&vt[((size_t)(b * H_ + h) * D_ + d) * T_ + tb + t0] = pw;
    }
  } else {
#pragma unroll
    for (int m = 0; m < 4; m++) {
#pragma unroll
      for (int n = 0; n < 4; n++) {
#pragma unroll
        for (int r = 0; r < 4; r++) {
          long i = i0 + wr*64 + m*16 + lhi*4 + r;
          int  j = (int)j0 + wc*64 + n*16 + l15;
          float v = acc[m][n][r] + bias[j];
          if (MODE == 0) {
            int b = (int)(i >> 11), t = (int)(i & 2047);
            int cc = j & 1023;
            int h = cc >> 6, d = cc & 63;
            long bh = (long)b * H_ + h;
            if (j < 1024)      q [(bh*T_ + t)*D_ + d] = f2bf(v * SCALE_LOG2);
            else               kk[(bh*T_ + t)*D_ + d] = f2bf(v);
          } else {
            outF[i * C_ + j] = v;
          }
        }
      }
    }
  }
}

// ---- causal flash attention, single-band waves, KVBLK=64, QK-upfront ----
// 1024 blocks x 256 threads (4 waves). head = bb&63 (8 heads/XCD), rblk =
// 15-(bb>>6) (longest-first backfill). Wave w: rows [128*rblk+32w, +31];
// nst = 2*rblk+2 tiles of 64 kv. K/Vt [64][64] dbuf (counted vmcnt(4), XOR
// granule swizzle) + P2 = 43KB -> 3 blocks/CU. Per tile: BOTH 32-kv chunks'
// K-frags + QK MFMAs issue UP FRONT (independent streams; chunk 1's QK hides
// under chunk 0's softmax), then sm->P->PV per chunk (shared P buffer,
// compiler-scheduled DS ordering). PV = mfma32(Vt, P).
#define PSTR 20   // u32 per q-row: 16 pairs + 4 pad

static __device__ __forceinline__ void softmax_pack32(
    f32x16& sc, float& m, float& lp, f32x16 (&o)[2],
    int q0, int kvbase, int l31, int hi, uint* __restrict__ P)
{
  float sv[16];
  const bool needmask = (kvbase + 31 > q0);
#pragma unroll
  for (int r = 0; r < 16; r++) {
    float xv = sc[r];
    if (needmask) {
      int kv = kvbase + (r & 3) + 8 * (r >> 2) + 4 * hi;
      if (kv > q0 + l31) xv = -1e30f;
    }
    sv[r] = xv;
  }
  float a0 = fmaxf(fmaxf(sv[0], sv[1]), sv[2]);
  float a1 = fmaxf(fmaxf(sv[3], sv[4]), sv[5]);
  float a2 = fmaxf(fmaxf(sv[6], sv[7]), sv[8]);
  float a3 = fmaxf(fmaxf(sv[9], sv[10]), sv[11]);
  float a4 = fmaxf(fmaxf(sv[12], sv[13]), sv[14]);
  float pmax = fmaxf(fmaxf(fmaxf(a0, a1), a2), fmaxf(fmaxf(a3, a4), sv[15]));
  if (__any(pmax > m + 8.0f)) {        // rare rescale
    float rowm = pair_max(pmax);
    float nm = fmaxf(m, rowm);
    float alpha = __builtin_amdgcn_exp2f(m - nm);
    m = nm;
    lp *= alpha;
#pragma unroll
    for (int dt = 0; dt < 2; dt++)
#pragma unroll
      for (int r = 0; r < 16; r++) o[dt][r] *= alpha;
  }
  float s = 0.f;
#pragma unroll
  for (int r = 0; r < 16; r++) {
    float p = __builtin_amdgcn_exp2f(sv[r] - m);
    sv[r] = p;
    s += p;
  }
  lp += s;
  uint W[8];
#pragma unroll
  for (int r = 0; r < 8; r++)
    asm("v_cvt_pk_bf16_f32 %0, %1, %2" : "=v"(W[r]) : "v"(sv[2*r]), "v"(sv[2*r+1]));
#pragma unroll
  for (int r2 = 0; r2 < 4; r2++) {
    uint2 pr; pr.x = W[2*r2]; pr.y = W[2*r2 + 1];
    *(uint2*)&P[l31 * PSTR + r2*4 + 2*hi] = pr;
  }
}

__global__ __launch_bounds__(256, 3) void attn_k(
    const ushort* __restrict__ Q, const ushort* __restrict__ K,
    const ushort* __restrict__ V, ushort* __restrict__ AO)
{
  __shared__ ushort Kt[2][64*64];
  __shared__ ushort Vt[2][64*64];
  __shared__ uint P2[4][32 * PSTR];
  const int tid = threadIdx.x;
  const int lane = tid & 63;
  const int w = tid >> 6;              // 0..3
  const int l31 = lane & 31, hi = lane >> 5;
  const int bb = blockIdx.x;
  const int head = bb & 63;            // bb%8 = head%8 -> same-head same XCD
  const int rblk = 15 - (bb >> 6);     // longest-first launch order
  const int nst = 2 * rblk + 2;        // 64-kv tiles
  const int q0 = 128 * rblk + 32 * w;

  const ushort* Qb = Q + (size_t)head * T_ * D_;
  const ushort* Kb = K + (size_t)head * T_ * D_;
  const ushort* Vb = V + (size_t)head * D_ * T_;   // [d][t]

  auto STAGE = [&](int buf, int kv0s) {
#pragma unroll
    for (int hb = 0; hb < 2; hb++) {
      int slot = tid + hb * 256;            // 0..511
      int row = slot >> 3, g = slot & 7, gs = g ^ (row & 7);
      ld16((const char*)Kb + ((size_t)(kv0s + row) * D_ + gs * 8) * 2,
           (char*)&Kt[buf][0] + slot * 16);
      ld16((const char*)Vb + ((size_t)row * T_ + kv0s + gs * 8) * 2,
           (char*)&Vt[buf][0] + slot * 16);
    }
  };

  // Q as B-fragment: lane holds Q[q0+l31][d = s*16 + hi*8 + e] per slice s.
  short8 qf[4];
#pragma unroll
  for (int s = 0; s < 4; s++)
    qf[s] = *(const short8*)&Qb[(q0 + l31) * D_ + s*16 + hi*8];

  f32x16 o[2] = {};          // O'[d][q]: d = dt*32 + (r&3)+8(r>>2)+4hi, q=l31
  float m = -1e30f, lp = 0.f;

  STAGE(0, 0);
  STAGE(1, 64);              // nst >= 2 always
  int cur = 0;
  uint* P = &P2[w][0];

  for (int t = 0; t < nst; t++) {
    const int kv0 = t * 64;
    if (t + 1 < nst) { asm volatile("s_waitcnt vmcnt(4)" ::: "memory"); }
    else             { asm volatile("s_waitcnt vmcnt(0)" ::: "memory"); }
    __builtin_amdgcn_s_barrier();
    __builtin_amdgcn_sched_barrier(0);

    const int kvc0 = kv0, kvc1 = kv0 + 32;
    const bool a0 = (kvc0 <= q0 + 31);
    const bool a1 = (kvc1 <= q0 + 31);

    // ---- phase 1: K-frags + QK MFMAs for BOTH chunks (independent) ----
    f32x16 sc0 = {}, sc1 = {};
    short8 vf0[2][2], vf1[2][2];
    if (a0) {
      short8 kf[4];
#pragma unroll
      for (int s = 0; s < 4; s++) {
        const int row = l31;                       // c=0
        kf[s] = *(const short8*)&Kt[cur][row*64 + (((2*s + hi) ^ (row & 7)) << 3)];
      }
      __builtin_amdgcn_s_setprio(1);
#pragma unroll
      for (int s = 0; s < 4; s++) sc0 = mfma32(kf[s], qf[s], sc0);
      __builtin_amdgcn_s_setprio(0);
    }
    if (a1) {
      short8 kf[4];
#pragma unroll
      for (int s = 0; s < 4; s++) {
        const int row = 32 + l31;                  // c=1
        kf[s] = *(const short8*)&Kt[cur][row*64 + (((2*s + hi) ^ (row & 7)) << 3)];
      }
      __builtin_amdgcn_s_setprio(1);
#pragma unroll
      for (int s = 0; s < 4; s++) sc1 = mfma32(kf[s], qf[s], sc1);
      __builtin_amdgcn_s_setprio(0);
    }
    // V-frags for both chunks (LDS latency hides under softmax below)
    if (a0) {
#pragma unroll
      for (int sl = 0; sl < 2; sl++)
#pragma unroll
        for (int dt = 0; dt < 2; dt++) {
          const int row = dt*32 + l31;
          const int u = sl*2 + hi;                 // c=0
          vf0[sl][dt] = *(const short8*)&Vt[cur][row*64 + ((u ^ (row & 7)) << 3)];
        }
    }
    if (a1) {
#pragma unroll
      for (int sl = 0; sl < 2; sl++)
#pragma unroll
        for (int dt = 0; dt < 2; dt++) {
          const int row = dt*32 + l31;
          const int u = 4 + sl*2 + hi;             // c=1
          vf1[sl][dt] = *(const short8*)&Vt[cur][row*64 + ((u ^ (row & 7)) << 3)];
        }
    }

    // ---- phase 2: softmax -> P -> PV per chunk (shared P buffer) ----
    if (a0) {
      softmax_pack32(sc0, m, lp, o, q0, kvc0, l31, hi, P);
      short8 pf[2];
#pragma unroll
      for (int sl = 0; sl < 2; sl++) {
        uint4 pw = *(const uint4*)&P[l31 * PSTR + sl*8 + hi*4];
        __builtin_memcpy(&pf[sl], &pw, 16);
      }
      __builtin_amdgcn_s_setprio(1);
#pragma unroll
      for (int dt = 0; dt < 2; dt++) {
        o[dt] = mfma32(vf0[0][dt], pf[0], o[dt]);
        o[dt] = mfma32(vf0[1][dt], pf[1], o[dt]);
      }
      __builtin_amdgcn_s_setprio(0);
    }
    if (a1) {
      softmax_pack32(sc1, m, lp, o, q0, kvc1, l31, hi, P);
      short8 pf[2];
#pragma unroll
      for (int sl = 0; sl < 2; sl++) {
        uint4 pw = *(const uint4*)&P[l31 * PSTR + sl*8 + hi*4];
        __builtin_memcpy(&pf[sl], &pw, 16);
      }
      __builtin_amdgcn_s_setprio(1);
#pragma unroll
      for (int dt = 0; dt < 2; dt++) {
        o[dt] = mfma32(vf1[0][dt], pf[0], o[dt]);
        o[dt] = mfma32(vf1[1][dt], pf[1], o[dt]);
      }
      __builtin_amdgcn_s_setprio(0);
    }

    __builtin_amdgcn_s_barrier();
    __builtin_amdgcn_sched_barrier(0);
    if (t + 2 < nst) STAGE(cur, kv0 + 128);   // overwrite freed buffer
    cur ^= 1;
  }

  const int b = head >> 4, h = head & 15;
  const float invl = 1.0f / pair_sum(lp);
  const size_t rowb = (size_t)(b * T_ + q0 + l31) * C_ + h * 64;
#pragma unroll
  for (int dt = 0; dt < 2; dt++)
#pragma unroll
    for (int rg = 0; rg < 4; rg++) {
      const int d0 = dt*32 + 8*rg + 4*hi;
      ushort4 ov;
      ov.x = f2bf(o[dt][rg*4+0] * invl);
      ov.y = f2bf(o[dt][rg*4+1] * invl);
      ov.z = f2bf(o[dt][rg*4+2] * invl);
      ov.w = f2bf(o[dt][rg*4+3] * invl);
      *(ushort4*)&AO[rowb + d0] = ov;
    }
}

extern "C" void kernel_launch(void* const* d_in, const int* in_sizes, int n_in,
                              void* d_out, int out_size, void* d_ws, size_t ws_size,
                              hipStream_t stream) {
  const float* x     = (const float*)d_in[0];
  const float* w_qkv = (const float*)d_in[1];
  const float* b_qkv = (const float*)d_in[2];
  const float* w_out = (const float*)d_in[3];
  const float* b_out = (const float*)d_in[4];
  float* out = (float*)d_out;

  ushort* xb    = (ushort*)d_ws;                    // 8192*1024
  ushort* wqkvb = xb    + (size_t)M_ * C_;          // 3072*1024
  ushort* woutb = wqkvb + (size_t)3 * C_ * C_;      // 1024*1024
  ushort* q     = woutb + (size_t)C_ * C_;          // [B,H,T,D] (exp2-domain scaled)
  ushort* kk    = q     + (size_t)M_ * C_;          // [B,H,T,D]
  ushort* vt    = kk    + (size_t)M_ * C_;          // [B,H,D,T]
  ushort* ao    = xb;                               // reuse xb (free after QKV GEMM)

  cvt3<<<2048, 256, 0, stream>>>(x, w_qkv, w_out, xb, wqkvb, woutb,
                                 (M_ * C_) / 4, (3 * C_ * C_) / 4, (C_ * C_) / 4);

  gemm_bt<0><<<dim3(3 * C_ / 128, M_ / 128), 256, 0, stream>>>(
      xb, wqkvb, b_qkv, C_, q, kk, vt, nullptr);

  // 4 waves x 32 rows = 128 rows per block, one band -> 1024 blocks.
  attn_k<<<B_ * H_ * T_ / 128, 256, 0, stream>>>(q, kk, vt, ao);

  gemm_bt<1><<<dim3(C_ / 128, M_ / 128), 256, 0, stream>>>(
      ao, woutb, b_out, C_, nullptr, nullptr, nullptr, out);
}